// Round 1
// baseline (2961.069 us; speedup 1.0000x reference)
//
#include <hip/hip_runtime.h>
#include <hip/hip_bf16.h>
#include <math.h>

// ---------------------------------------------------------------------------
// HydraFusionHead: B=4, IN_CH=256, HEAD_CH=64, H=W=128, NH=4, KEY=VAL=16
// All fp32. Strategy: fuse grid-sampling into the per-head 1x1 K/V convs
// (sample offsets are compile-time constants), BN folded into weights by a
// prep kernel, weights pre-transposed to [*, out] so inner loops are
// uniform s_load + v_fma_f32.
// ---------------------------------------------------------------------------

#define HW 16384
#define WIMG 128

// ws layout (float offsets)
constexpr size_t OFF_FEATS = 0;                   // [4][192][HW] (center|corner|fg)
constexpr size_t OFF_Q     = 12582912;            // [4][64][HW]
constexpr size_t OFF_KV    = 16777216;            // [3][4][128][HW] (k:0..63, v:64..127)
constexpr size_t OFF_CWT   = 41943040;            // [3][256][9][64] folded conv weights
constexpr size_t OFF_CB    = OFF_CWT + 442368;    // [3][64]
constexpr size_t OFF_HWT_C = OFF_CB + 192;        // [64][9][3]
constexpr size_t OFF_HWT_O = OFF_HWT_C + 1728;    // [64][9][12]
constexpr size_t OFF_HWT_F = OFF_HWT_O + 6912;    // [64][9][3]
constexpr size_t OFF_QWT   = OFF_HWT_F + 1728;    // [256][64]
constexpr size_t OFF_QB    = OFF_QWT + 16384;     // [64]
constexpr size_t OFF_KVWT  = OFF_QB + 64;         // [3][624][128]
constexpr size_t OFF_KVB   = OFF_KVWT + 239616;   // [3][128]
constexpr size_t OFF_P1WT  = OFF_KVB + 384;       // [272][256]
constexpr size_t OFF_P1B   = OFF_P1WT + 69632;    // [256]
constexpr size_t WS_FLOATS = OFF_P1B + 256;       // ~42.72M floats (~163 MB)

struct P53 { const float* p[53]; };

// --------------------------- prep: fold BN + transpose ----------------------
__global__ __launch_bounds__(256) void prep_kernel(P53 ptrs, float* __restrict__ ws) {
    int i = blockIdx.x * 256 + threadIdx.x;
    const float* const* p = ptrs.p;
    // conv_wt [3][256][9][64]: w' = w * s
    if (i < 442368) {
        int oc = i & 63, k = (i >> 6) % 9, c = (i / 576) & 255, br = i / 147456;
        const float* w = p[1 + 6 * br]; const float* s = p[3 + 6 * br];
        ws[OFF_CWT + i] = w[(oc * 256 + c) * 9 + k] * s[oc];
        return;
    }
    i -= 442368;
    if (i < 192) {  // conv bias: b*s + t
        int br = i >> 6, oc = i & 63;
        ws[OFF_CB + i] = p[2 + 6 * br][oc] * p[3 + 6 * br][oc] + p[4 + 6 * br][oc];
        return;
    }
    i -= 192;
    if (i < 1728) { int o = i % 3, k = (i / 3) % 9, c = i / 27;
        ws[OFF_HWT_C + i] = p[5][(o * 64 + c) * 9 + k]; return; }
    i -= 1728;
    if (i < 6912) { int o = i % 12, k = (i / 12) % 9, c = i / 108;
        ws[OFF_HWT_O + i] = p[11][(o * 64 + c) * 9 + k]; return; }
    i -= 6912;
    if (i < 1728) { int o = i % 3, k = (i / 3) % 9, c = i / 27;
        ws[OFF_HWT_F + i] = p[17][(o * 64 + c) * 9 + k]; return; }
    i -= 1728;
    if (i < 16384) { int o = i & 63, c = i >> 6;
        ws[OFF_QWT + i] = p[19][o * 256 + c] * p[21][o]; return; }
    i -= 16384;
    if (i < 64) { ws[OFF_QB + i] = p[20][i] * p[21][i] + p[22][i]; return; }
    i -= 64;
    if (i < 239616) {  // kv_wt [3][624][128]
        int o = i & 127, cp = (i >> 7) % 624, br = i / 79872;
        int Cn = (br == 1) ? 624 : 621;
        float v = 0.f;
        if (cp < Cn) {
            if (o < 64) v = p[23 + 8 * br][o * Cn + cp] * p[25 + 8 * br][o];
            else { int o2 = o - 64; v = p[27 + 8 * br][o2 * Cn + cp] * p[29 + 8 * br][o2]; }
        }
        ws[OFF_KVWT + i] = v; return;
    }
    i -= 239616;
    if (i < 384) {
        int br = i / 128, o = i % 128;
        float v = (o < 64)
            ? p[24 + 8 * br][o] * p[25 + 8 * br][o] + p[26 + 8 * br][o]
            : p[28 + 8 * br][o - 64] * p[29 + 8 * br][o - 64] + p[30 + 8 * br][o - 64];
        ws[OFF_KVB + i] = v; return;
    }
    i -= 384;
    if (i < 69632) { int o = i & 255, c = i >> 8;
        ws[OFF_P1WT + i] = p[47][o * 272 + c] * p[49][o]; return; }
    i -= 69632;
    if (i < 256) { ws[OFF_P1B + i] = p[48][i] * p[49][i] + p[50][i]; return; }
}

// ------------------- conv3x3 base(256) -> 3x64 feats, BN+ReLU ---------------
__global__ __launch_bounds__(256) void conv_base_kernel(
    const float* __restrict__ base, const float* __restrict__ cwt,
    const float* __restrict__ cb, float* __restrict__ feats)
{
    const int tx = threadIdx.x & 15, ty = threadIdx.x >> 4;
    const int w0 = blockIdx.x << 4, h0 = blockIdx.y << 4;
    const int br = blockIdx.z % 3, b = blockIdx.z / 3;
    const float* wt = cwt + br * 147456;
    __shared__ float tile[4][18][18];
    float acc[64];
    #pragma unroll
    for (int o = 0; o < 64; ++o) acc[o] = cb[br * 64 + o];
    const float* inb = base + (size_t)b * 256 * HW;
    for (int c0 = 0; c0 < 256; c0 += 4) {
        __syncthreads();
        for (int i = threadIdx.x; i < 1296; i += 256) {
            int cc = i / 324, r = (i % 324) / 18, col = i % 18;
            int gh = h0 + r - 1, gw = w0 + col - 1;
            float v = 0.f;
            if ((unsigned)gh < 128u && (unsigned)gw < 128u)
                v = inb[(c0 + cc) * HW + gh * WIMG + gw];
            tile[cc][r][col] = v;
        }
        __syncthreads();
        #pragma unroll
        for (int cc = 0; cc < 4; ++cc) {
            float in[9];
            #pragma unroll
            for (int ky = 0; ky < 3; ++ky)
                #pragma unroll
                for (int kx = 0; kx < 3; ++kx)
                    in[ky * 3 + kx] = tile[cc][ty + ky][tx + kx];
            const float* wr = wt + (c0 + cc) * 576;
            #pragma unroll
            for (int k = 0; k < 9; ++k) {
                #pragma unroll
                for (int o = 0; o < 64; ++o)
                    acc[o] = fmaf(wr[k * 64 + o], in[k], acc[o]);
            }
        }
    }
    float* ob = feats + ((size_t)b * 192 + br * 64) * HW + (h0 + ty) * WIMG + (w0 + tx);
    #pragma unroll
    for (int o = 0; o < 64; ++o) ob[o * HW] = fmaxf(acc[o], 0.f);
}

// ---------------- head 3x3 convs (64 -> 3/12/3) -> d_out ch 0..17 -----------
template<int CNT, int BASE>
__device__ inline void head_accum(float (&acc)[18], const float* __restrict__ fb,
                                  int cbase, const float* __restrict__ hwt,
                                  float (&tile)[4][18][18],
                                  int tx, int ty, int h0, int w0)
{
    for (int c0 = 0; c0 < 64; c0 += 4) {
        __syncthreads();
        for (int i = threadIdx.x; i < 1296; i += 256) {
            int cc = i / 324, r = (i % 324) / 18, col = i % 18;
            int gh = h0 + r - 1, gw = w0 + col - 1;
            float v = 0.f;
            if ((unsigned)gh < 128u && (unsigned)gw < 128u)
                v = fb[(cbase + c0 + cc) * HW + gh * WIMG + gw];
            tile[cc][r][col] = v;
        }
        __syncthreads();
        #pragma unroll
        for (int cc = 0; cc < 4; ++cc) {
            float in[9];
            #pragma unroll
            for (int ky = 0; ky < 3; ++ky)
                #pragma unroll
                for (int kx = 0; kx < 3; ++kx)
                    in[ky * 3 + kx] = tile[cc][ty + ky][tx + kx];
            const float* wr = hwt + (c0 + cc) * 9 * CNT;
            #pragma unroll
            for (int k = 0; k < 9; ++k) {
                #pragma unroll
                for (int j = 0; j < CNT; ++j)
                    acc[BASE + j] = fmaf(wr[k * CNT + j], in[k], acc[BASE + j]);
            }
        }
    }
}

__global__ __launch_bounds__(256) void conv_head_kernel(
    const float* __restrict__ feats, const float* __restrict__ ws,
    const float* __restrict__ chb, const float* __restrict__ ohb,
    const float* __restrict__ fhb, float* __restrict__ out)
{
    const int tx = threadIdx.x & 15, ty = threadIdx.x >> 4;
    const int w0 = blockIdx.x << 4, h0 = blockIdx.y << 4;
    const int b = blockIdx.z;
    __shared__ float tile[4][18][18];
    float acc[18];
    #pragma unroll
    for (int j = 0; j < 3; ++j)  acc[j]      = chb[j];
    #pragma unroll
    for (int j = 0; j < 12; ++j) acc[3 + j]  = ohb[j];
    #pragma unroll
    for (int j = 0; j < 3; ++j)  acc[15 + j] = fhb[j];
    const float* fb = feats + (size_t)b * 192 * HW;
    head_accum<3, 0> (acc, fb, 0,   ws + OFF_HWT_C, tile, tx, ty, h0, w0);
    head_accum<12, 3>(acc, fb, 64,  ws + OFF_HWT_O, tile, tx, ty, h0, w0);
    head_accum<3, 15>(acc, fb, 128, ws + OFF_HWT_F, tile, tx, ty, h0, w0);
    float* ob = out + (size_t)b * 26 * HW + (h0 + ty) * WIMG + (w0 + tx);
    #pragma unroll
    for (int ch = 0; ch < 18; ++ch) ob[ch * HW] = acc[ch];
}

// ----------------------------- q (per-head 1x1) -----------------------------
__global__ __launch_bounds__(256) void q_kernel(const float* __restrict__ base,
                                                float* __restrict__ ws)
{
    const int px = blockIdx.x * 256 + threadIdx.x;
    const int b = blockIdx.y;
    const float* qwt = ws + OFF_QWT;
    const float* qb  = ws + OFF_QB;
    float acc[64];
    #pragma unroll
    for (int o = 0; o < 64; ++o) acc[o] = qb[o];
    const float* inb = base + (size_t)b * 256 * HW + px;
    #pragma unroll 4
    for (int c = 0; c < 256; ++c) {
        float v = inb[c * HW];
        const float* wr = qwt + c * 64;
        #pragma unroll
        for (int o = 0; o < 64; ++o) acc[o] = fmaf(wr[o], v, acc[o]);
    }
    float* q = ws + OFF_Q + (size_t)b * 64 * HW + px;
    #pragma unroll
    for (int o = 0; o < 64; ++o) q[o * HW] = fmaxf(acc[o], 0.f);
}

// ------------------ fused sampling + per-head 1x1 K/V conv ------------------
// Sample offsets (compile-time, faithful to the torch .view(2,n) reinterpret)
__device__ const float c_ox[3][9] = {
    {-1.f, 0.f, 1.f, -1.f, 0.f, 1.f, -1.f, 0.f, 1.f},
    {-1.f, 2.4375f, -1.f, -2.4375f, 1.f, 2.4375f, 1.f, -2.4375f, 0.f},
    {-1.625f, -1.625f, -1.625f, 0.f, -1.625f, 1.625f, 0.f, -1.625f, 0.f}};
__device__ const float c_oy[3][9] = {
    {-1.f, -1.f, -1.f, 0.f, 0.f, 0.f, 1.f, 1.f, 1.f},
    {2.4375f, -1.f, -2.4375f, -1.f, 2.4375f, 1.f, -2.4375f, 1.f, 0.f},
    {0.f, 0.f, 1.625f, 1.625f, -1.625f, 1.625f, 0.f, 1.625f, 1.625f}};
__device__ const int c_n[3]       = {9, 8, 9};
__device__ const int c_C[3]       = {67, 76, 67};
__device__ const int c_mapbase[3] = {0, 3, 15};

__global__ __launch_bounds__(256) void kv_kernel(float* __restrict__ ws,
                                                 const float* __restrict__ out)
{
    const int px = blockIdx.x * 256 + threadIdx.x;
    const int b = blockIdx.y;
    const int br = blockIdx.z >> 1, half = blockIdx.z & 1;
    const int h = px >> 7, w = px & 127;
    const float* feats = ws + OFF_FEATS + ((size_t)b * 192 + br * 64) * HW;
    const float* maps  = out + ((size_t)b * 26 + c_mapbase[br]) * HW;
    const float* wtb   = ws + OFF_KVWT + (size_t)br * 79872 + half * 64;
    const float* kvb   = ws + OFF_KVB + br * 128 + half * 64;
    const int n = c_n[br], C = c_C[br];
    float acc[64];
    #pragma unroll
    for (int o = 0; o < 64; ++o) acc[o] = kvb[o];
    for (int p = 0; p < n; ++p) {
        float ox = c_ox[br][p], oy = c_oy[br][p];
        float fox = floorf(ox), foy = floorf(oy);
        int ix = (int)fox, iy = (int)foy;
        float dx = ox - fox, dy = oy - foy;
        int x0 = w + ix, y0 = h + iy;
        float w00 = (1.f - dx) * (1.f - dy), w10 = dx * (1.f - dy);
        float w01 = (1.f - dx) * dy,         w11 = dx * dy;
        bool vx0 = (unsigned)x0 < 128u, vx1 = (unsigned)(x0 + 1) < 128u;
        bool vy0 = (unsigned)y0 < 128u, vy1 = (unsigned)(y0 + 1) < 128u;
        float m00 = (vx0 && vy0) ? w00 : 0.f, m10 = (vx1 && vy0) ? w10 : 0.f;
        float m01 = (vx0 && vy1) ? w01 : 0.f, m11 = (vx1 && vy1) ? w11 : 0.f;
        int cx0 = min(max(x0, 0), 127), cx1 = min(max(x0 + 1, 0), 127);
        int cy0 = min(max(y0, 0), 127), cy1 = min(max(y0 + 1, 0), 127);
        int a00 = cy0 * WIMG + cx0, a10 = cy0 * WIMG + cx1;
        int a01 = cy1 * WIMG + cx0, a11 = cy1 * WIMG + cx1;
        for (int c = 0; c < C; ++c) {
            const float* F = (c < 64) ? (feats + c * HW) : (maps + (c - 64) * HW);
            float S = m00 * F[a00] + m10 * F[a10] + m01 * F[a01] + m11 * F[a11];
            const float* wr = wtb + (c * n + p) * 128;
            #pragma unroll
            for (int o = 0; o < 64; ++o) acc[o] = fmaf(wr[o], S, acc[o]);
        }
        float gx = (w + 0.5f + ox) * (1.0f / 128.0f);
        float gy = (h + 0.5f + oy) * (1.0f / 128.0f);
        const float* wrx = wtb + (C * n + p) * 128;
        const float* wry = wtb + ((C + 1) * n + p) * 128;
        #pragma unroll
        for (int o = 0; o < 64; ++o) acc[o] = fmaf(wrx[o], gx, acc[o]);
        #pragma unroll
        for (int o = 0; o < 64; ++o) acc[o] = fmaf(wry[o], gy, acc[o]);
    }
    float* kv = ws + OFF_KV;
    const int ob = (br * 4 + b) * 128 + half * 64;
    #pragma unroll
    for (int o = 0; o < 64; ++o)
        kv[(size_t)(ob + o) * HW + px] = fmaxf(acc[o], 0.f);
}

// ------------------- attention (softmax over 3) + predict -------------------
__global__ __launch_bounds__(256) void attn_pred_kernel(
    const float* __restrict__ base, float* __restrict__ ws,
    const float* __restrict__ p2w, const float* __restrict__ p2b,
    float* __restrict__ out)
{
    const int px = blockIdx.x * 256 + threadIdx.x;
    const int b = blockIdx.y;
    const float* q  = ws + OFF_Q + (size_t)b * 64 * HW + px;
    const float* kv = ws + OFF_KV;
    float aw[4][3];
    #pragma unroll
    for (int nh = 0; nh < 4; ++nh) {
        float l0 = 0.f, l1 = 0.f, l2 = 0.f;
        #pragma unroll
        for (int ko = 0; ko < 16; ++ko) {
            float qv = q[(nh * 16 + ko) * HW];
            l0 = fmaf(qv, kv[(size_t)((0 * 4 + b) * 128 + nh * 16 + ko) * HW + px], l0);
            l1 = fmaf(qv, kv[(size_t)((1 * 4 + b) * 128 + nh * 16 + ko) * HW + px], l1);
            l2 = fmaf(qv, kv[(size_t)((2 * 4 + b) * 128 + nh * 16 + ko) * HW + px], l2);
        }
        float m = fmaxf(l0, fmaxf(l1, l2));
        float e0 = expf(l0 - m), e1 = expf(l1 - m), e2 = expf(l2 - m);
        float inv = 1.f / (e0 + e1 + e2);
        aw[nh][0] = e0 * inv; aw[nh][1] = e1 * inv; aw[nh][2] = e2 * inv;
    }
    const float* p1wt = ws + OFF_P1WT;
    const float* p1b  = ws + OFF_P1B;
    const float* inb  = base + (size_t)b * 256 * HW + px;
    #pragma unroll
    for (int nh = 0; nh < 4; ++nh) {
        float attn[16];
        #pragma unroll
        for (int va = 0; va < 16; ++va) {
            attn[va] =
                aw[nh][0] * kv[(size_t)((0 * 4 + b) * 128 + 64 + nh * 16 + va) * HW + px] +
                aw[nh][1] * kv[(size_t)((1 * 4 + b) * 128 + 64 + nh * 16 + va) * HW + px] +
                aw[nh][2] * kv[(size_t)((2 * 4 + b) * 128 + 64 + nh * 16 + va) * HW + px];
        }
        float acc[64];
        #pragma unroll
        for (int j = 0; j < 64; ++j) acc[j] = p1b[nh * 64 + j];
        #pragma unroll 4
        for (int c = 0; c < 256; ++c) {
            float v = inb[c * HW];
            const float* wr = p1wt + c * 256 + nh * 64;
            #pragma unroll
            for (int j = 0; j < 64; ++j) acc[j] = fmaf(wr[j], v, acc[j]);
        }
        #pragma unroll
        for (int va = 0; va < 16; ++va) {
            const float* wr = p1wt + (256 + va) * 256 + nh * 64;
            #pragma unroll
            for (int j = 0; j < 64; ++j) acc[j] = fmaf(wr[j], attn[va], acc[j]);
        }
        float o0 = p2b[nh * 2 + 0], o1 = p2b[nh * 2 + 1];
        #pragma unroll
        for (int j = 0; j < 64; ++j) {
            float hj = fmaxf(acc[j], 0.f);
            o0 = fmaf(p2w[(nh * 2 + 0) * 64 + j], hj, o0);
            o1 = fmaf(p2w[(nh * 2 + 1) * 64 + j], hj, o1);
        }
        out[((size_t)b * 26 + 18 + nh * 2) * HW + px] = o0;
        out[((size_t)b * 26 + 19 + nh * 2) * HW + px] = o1;
    }
}

// ---------------------------------------------------------------------------
extern "C" void kernel_launch(void* const* d_in, const int* in_sizes, int n_in,
                              void* d_out, int out_size, void* d_ws, size_t ws_size,
                              hipStream_t stream) {
    (void)in_sizes; (void)n_in; (void)out_size; (void)ws_size;
    float* ws  = (float*)d_ws;
    float* out = (float*)d_out;
    const float* base = (const float*)d_in[0];
    P53 ptrs;
    for (int i = 0; i < 53; ++i) ptrs.p[i] = (const float*)d_in[i];

    // fold BN, transpose weights
    prep_kernel<<<3044, 256, 0, stream>>>(ptrs, ws);
    // three branch convs (256->64 each) + BN + relu
    conv_base_kernel<<<dim3(8, 8, 12), 256, 0, stream>>>(base, ws + OFF_CWT, ws + OFF_CB,
                                                         ws + OFF_FEATS);
    // head maps -> d_out channels 0..17 (also consumed by the sampler)
    conv_head_kernel<<<dim3(8, 8, 4), 256, 0, stream>>>(ws + OFF_FEATS, ws,
                                                        (const float*)d_in[6],
                                                        (const float*)d_in[12],
                                                        (const float*)d_in[18], out);
    // q projection
    q_kernel<<<dim3(64, 4), 256, 0, stream>>>(base, ws);
    // fused sampling + K/V projections (z: branch*2 + half(k|v))
    kv_kernel<<<dim3(64, 4, 6), 256, 0, stream>>>(ws, out);
    // attention + predict MLP -> d_out channels 18..25
    attn_pred_kernel<<<dim3(64, 4), 256, 0, stream>>>(base, ws, (const float*)d_in[51],
                                                      (const float*)d_in[52], out);
}

// Round 2
// 1826.326 us; speedup vs baseline: 1.6213x; 1.6213x over previous
//
#include <hip/hip_runtime.h>
#include <hip/hip_bf16.h>
#include <math.h>

// ---------------------------------------------------------------------------
// HydraFusionHead: B=4, IN_CH=256, HEAD_CH=64, H=W=128, NH=4, KEY=VAL=16
// conv_base now runs as bf16 MFMA implicit GEMM (all 3 branches fused, M=192,
// K=2304 tap-major). Everything else fp32 VALU. BN folded by prep.
// ---------------------------------------------------------------------------

#define HW 16384
#define WIMG 128

typedef unsigned short ushortT;
typedef __attribute__((ext_vector_type(8))) short short8;
typedef __attribute__((ext_vector_type(4))) float floatx4;

// ws layout (float offsets)
constexpr size_t OFF_FEATS = 0;                   // [4][192][HW] (center|corner|fg)
constexpr size_t OFF_Q     = 12582912;            // [4][64][HW]
constexpr size_t OFF_KV    = 16777216;            // [3][4][128][HW] (k:0..63, v:64..127)
constexpr size_t OFF_CWT   = 41943040;            // bf16 wA [9][32][192][8] (442368 ushort)
constexpr size_t OFF_CB    = OFF_CWT + 442368;    // [3][64] fp32 bias (idx = br*64+oc)
constexpr size_t OFF_HWT_C = OFF_CB + 192;        // [64][9][3]
constexpr size_t OFF_HWT_O = OFF_HWT_C + 1728;    // [64][9][12]
constexpr size_t OFF_HWT_F = OFF_HWT_O + 6912;    // [64][9][3]
constexpr size_t OFF_QWT   = OFF_HWT_F + 1728;    // [256][64]
constexpr size_t OFF_QB    = OFF_QWT + 16384;     // [64]
constexpr size_t OFF_KVWT  = OFF_QB + 64;         // [3][624][128]
constexpr size_t OFF_KVB   = OFF_KVWT + 239616;   // [3][128]
constexpr size_t OFF_P1WT  = OFF_KVB + 384;       // [272][256]
constexpr size_t OFF_P1B   = OFF_P1WT + 69632;    // [256]

struct P53 { const float* p[53]; };

__device__ inline ushortT f2bf(float f) {
    unsigned u = __float_as_uint(f);
    unsigned r = (u + 0x7FFFu + ((u >> 16) & 1u)) >> 16;
    return (ushortT)r;
}

// --------------------------- prep: fold BN + transpose ----------------------
__global__ __launch_bounds__(256) void prep_kernel(P53 ptrs, float* __restrict__ ws) {
    int i = blockIdx.x * 256 + threadIdx.x;
    const float* const* p = ptrs.p;
    // bf16 conv weights wA[tap][g(32)][M(192)][j(8)], M = br*64+oc, ic = g*8+j
    if (i < 442368) {
        int tap = i / 49152, r = i % 49152;
        int g = r / 1536, r2 = r % 1536;
        int M = r2 >> 3, j = r2 & 7;
        int br = M >> 6, oc = M & 63, ic = g * 8 + j;
        float v = p[1 + 6 * br][(oc * 256 + ic) * 9 + tap] * p[3 + 6 * br][oc];
        ((ushortT*)(ws + OFF_CWT))[i] = f2bf(v);
        return;
    }
    i -= 442368;
    if (i < 192) {  // conv bias: b*s + t
        int br = i >> 6, oc = i & 63;
        ws[OFF_CB + i] = p[2 + 6 * br][oc] * p[3 + 6 * br][oc] + p[4 + 6 * br][oc];
        return;
    }
    i -= 192;
    if (i < 1728) { int o = i % 3, k = (i / 3) % 9, c = i / 27;
        ws[OFF_HWT_C + i] = p[5][(o * 64 + c) * 9 + k]; return; }
    i -= 1728;
    if (i < 6912) { int o = i % 12, k = (i / 12) % 9, c = i / 108;
        ws[OFF_HWT_O + i] = p[11][(o * 64 + c) * 9 + k]; return; }
    i -= 6912;
    if (i < 1728) { int o = i % 3, k = (i / 3) % 9, c = i / 27;
        ws[OFF_HWT_F + i] = p[17][(o * 64 + c) * 9 + k]; return; }
    i -= 1728;
    if (i < 16384) { int o = i & 63, c = i >> 6;
        ws[OFF_QWT + i] = p[19][o * 256 + c] * p[21][o]; return; }
    i -= 16384;
    if (i < 64) { ws[OFF_QB + i] = p[20][i] * p[21][i] + p[22][i]; return; }
    i -= 64;
    if (i < 239616) {  // kv_wt [3][624][128]
        int o = i & 127, cp = (i >> 7) % 624, br = i / 79872;
        int Cn = (br == 1) ? 624 : 621;
        float v = 0.f;
        if (cp < Cn) {
            if (o < 64) v = p[23 + 8 * br][o * Cn + cp] * p[25 + 8 * br][o];
            else { int o2 = o - 64; v = p[27 + 8 * br][o2 * Cn + cp] * p[29 + 8 * br][o2]; }
        }
        ws[OFF_KVWT + i] = v; return;
    }
    i -= 239616;
    if (i < 384) {
        int br = i / 128, o = i % 128;
        float v = (o < 64)
            ? p[24 + 8 * br][o] * p[25 + 8 * br][o] + p[26 + 8 * br][o]
            : p[28 + 8 * br][o - 64] * p[29 + 8 * br][o - 64] + p[30 + 8 * br][o - 64];
        ws[OFF_KVB + i] = v; return;
    }
    i -= 384;
    if (i < 69632) { int o = i & 255, c = i >> 8;
        ws[OFF_P1WT + i] = p[47][o * 272 + c] * p[49][o]; return; }
    i -= 69632;
    if (i < 256) { ws[OFF_P1B + i] = p[48][i] * p[49][i] + p[50][i]; return; }
}

// ------------- conv3x3 base(256) -> 192 feats via bf16 MFMA -----------------
// Block: 4 waves, computes M=192 (3 branches x 64 oc) x N=64 px (half a row).
// K = 2304 ordered tap-major: chunk = 1 tap x 32 ic. Input tile staged in LDS
// as 16B elements [icg8][row3][col66] (8 consecutive ics per element).
__global__ __launch_bounds__(256) void conv_base_mfma(
    const float* __restrict__ base, const ushortT* __restrict__ wA,
    const float* __restrict__ cb, float* __restrict__ feats)
{
    const int wv = threadIdx.x >> 6, lane = threadIdx.x & 63;
    const int sub = lane >> 4, ln = lane & 15;
    const int xh = blockIdx.x, h = blockIdx.y, b = blockIdx.z;
    __shared__ __align__(16) ushortT sbuf[8 * 3 * 66 * 8];  // 25,344 B

    floatx4 acc[3][4];
    #pragma unroll
    for (int mt = 0; mt < 3; ++mt)
        #pragma unroll
        for (int nt = 0; nt < 4; ++nt)
            #pragma unroll
            for (int r = 0; r < 4; ++r) acc[mt][nt][r] = 0.f;

    const float* inb = base + (size_t)b * 256 * HW;
    const int icp = threadIdx.x & 3;  // constant across staging iters

    for (int s = 0; s < 4; ++s) {
        const int icbase = s * 64;
        __syncthreads();
        // stage 64 ics: 1584 elements x 4 words = 6336 word-writes, wave-linear
        for (int it = 0; it < 25; ++it) {
            int idx = threadIdx.x + it * 256;
            if (idx < 6336) {
                int elem = idx >> 2;
                int c = elem % 66, t2 = elem / 66;
                int r = t2 % 3, icg = t2 / 3;
                int gh = h + r - 1, gw = xh * 64 + c - 1;
                int ic = icbase + icg * 8 + icp * 2;
                float v0 = 0.f, v1 = 0.f;
                if ((unsigned)gh < 128u && (unsigned)gw < 128u) {
                    const float* pp = inb + (size_t)ic * HW + gh * WIMG + gw;
                    v0 = pp[0]; v1 = pp[HW];
                }
                ((unsigned*)sbuf)[idx] = (unsigned)f2bf(v0) | ((unsigned)f2bf(v1) << 16);
            }
        }
        __syncthreads();
        #pragma unroll
        for (int tap = 0; tap < 9; ++tap) {
            const int ky = tap / 3, kx = tap % 3;
            #pragma unroll
            for (int icc = 0; icc < 2; ++icc) {
                const int icgl = icc * 4 + sub;
                short8 Bf[4];
                #pragma unroll
                for (int nt = 0; nt < 4; ++nt) {
                    int c = nt * 16 + ln + kx;
                    int elem = (icgl * 3 + ky) * 66 + c;
                    Bf[nt] = *(const short8*)(sbuf + elem * 8);
                }
                const int g = s * 8 + icc * 4 + sub;
                short8 Af[3];
                #pragma unroll
                for (int mt = 0; mt < 3; ++mt) {
                    int m = wv * 48 + mt * 16 + ln;
                    Af[mt] = *(const short8*)(wA + (((size_t)tap * 32 + g) * 192 + m) * 8);
                }
                #pragma unroll
                for (int mt = 0; mt < 3; ++mt)
                    #pragma unroll
                    for (int nt = 0; nt < 4; ++nt)
                        acc[mt][nt] = __builtin_amdgcn_mfma_f32_16x16x32_bf16(
                            Af[mt], Bf[nt], acc[mt][nt], 0, 0, 0);
            }
        }
    }
    // epilogue: bias + relu, C/D layout col=lane&15, row=(lane>>4)*4+reg
    #pragma unroll
    for (int mt = 0; mt < 3; ++mt) {
        #pragma unroll
        for (int nt = 0; nt < 4; ++nt) {
            #pragma unroll
            for (int r = 0; r < 4; ++r) {
                int Mi = wv * 48 + mt * 16 + sub * 4 + r;
                int px = xh * 64 + nt * 16 + ln;
                float v = acc[mt][nt][r] + cb[Mi];
                feats[((size_t)b * 192 + Mi) * HW + h * WIMG + px] = fmaxf(v, 0.f);
            }
        }
    }
}

// ---------------- head 3x3 convs (64 -> 3/12/3) -> d_out ch 0..17 -----------
template<int CNT, int BASE>
__device__ inline void head_accum(float (&acc)[18], const float* __restrict__ fb,
                                  int cbase, const float* __restrict__ hwt,
                                  float (&tile)[4][18][18],
                                  int tx, int ty, int h0, int w0)
{
    for (int c0 = 0; c0 < 64; c0 += 4) {
        __syncthreads();
        for (int i = threadIdx.x; i < 1296; i += 256) {
            int cc = i / 324, r = (i % 324) / 18, col = i % 18;
            int gh = h0 + r - 1, gw = w0 + col - 1;
            float v = 0.f;
            if ((unsigned)gh < 128u && (unsigned)gw < 128u)
                v = fb[(cbase + c0 + cc) * HW + gh * WIMG + gw];
            tile[cc][r][col] = v;
        }
        __syncthreads();
        #pragma unroll
        for (int cc = 0; cc < 4; ++cc) {
            float in[9];
            #pragma unroll
            for (int ky = 0; ky < 3; ++ky)
                #pragma unroll
                for (int kx = 0; kx < 3; ++kx)
                    in[ky * 3 + kx] = tile[cc][ty + ky][tx + kx];
            const float* wr = hwt + (c0 + cc) * 9 * CNT;
            #pragma unroll
            for (int k = 0; k < 9; ++k) {
                #pragma unroll
                for (int j = 0; j < CNT; ++j)
                    acc[BASE + j] = fmaf(wr[k * CNT + j], in[k], acc[BASE + j]);
            }
        }
    }
}

__global__ __launch_bounds__(256) void conv_head_kernel(
    const float* __restrict__ feats, const float* __restrict__ ws,
    const float* __restrict__ chb, const float* __restrict__ ohb,
    const float* __restrict__ fhb, float* __restrict__ out)
{
    const int tx = threadIdx.x & 15, ty = threadIdx.x >> 4;
    const int w0 = blockIdx.x << 4, h0 = blockIdx.y << 4;
    const int b = blockIdx.z;
    __shared__ float tile[4][18][18];
    float acc[18];
    #pragma unroll
    for (int j = 0; j < 3; ++j)  acc[j]      = chb[j];
    #pragma unroll
    for (int j = 0; j < 12; ++j) acc[3 + j]  = ohb[j];
    #pragma unroll
    for (int j = 0; j < 3; ++j)  acc[15 + j] = fhb[j];
    const float* fb = feats + (size_t)b * 192 * HW;
    head_accum<3, 0> (acc, fb, 0,   ws + OFF_HWT_C, tile, tx, ty, h0, w0);
    head_accum<12, 3>(acc, fb, 64,  ws + OFF_HWT_O, tile, tx, ty, h0, w0);
    head_accum<3, 15>(acc, fb, 128, ws + OFF_HWT_F, tile, tx, ty, h0, w0);
    float* ob = out + (size_t)b * 26 * HW + (h0 + ty) * WIMG + (w0 + tx);
    #pragma unroll
    for (int ch = 0; ch < 18; ++ch) ob[ch * HW] = acc[ch];
}

// ----------------------------- q (per-head 1x1) -----------------------------
__global__ __launch_bounds__(256) void q_kernel(const float* __restrict__ base,
                                                float* __restrict__ ws)
{
    const int px = blockIdx.x * 256 + threadIdx.x;
    const int b = blockIdx.y;
    const float* qwt = ws + OFF_QWT;
    const float* qb  = ws + OFF_QB;
    float acc[64];
    #pragma unroll
    for (int o = 0; o < 64; ++o) acc[o] = qb[o];
    const float* inb = base + (size_t)b * 256 * HW + px;
    #pragma unroll 4
    for (int c = 0; c < 256; ++c) {
        float v = inb[c * HW];
        const float* wr = qwt + c * 64;
        #pragma unroll
        for (int o = 0; o < 64; ++o) acc[o] = fmaf(wr[o], v, acc[o]);
    }
    float* q = ws + OFF_Q + (size_t)b * 64 * HW + px;
    #pragma unroll
    for (int o = 0; o < 64; ++o) q[o * HW] = fmaxf(acc[o], 0.f);
}

// ------------------ fused sampling + per-head 1x1 K/V conv ------------------
__device__ const float c_ox[3][9] = {
    {-1.f, 0.f, 1.f, -1.f, 0.f, 1.f, -1.f, 0.f, 1.f},
    {-1.f, 2.4375f, -1.f, -2.4375f, 1.f, 2.4375f, 1.f, -2.4375f, 0.f},
    {-1.625f, -1.625f, -1.625f, 0.f, -1.625f, 1.625f, 0.f, -1.625f, 0.f}};
__device__ const float c_oy[3][9] = {
    {-1.f, -1.f, -1.f, 0.f, 0.f, 0.f, 1.f, 1.f, 1.f},
    {2.4375f, -1.f, -2.4375f, -1.f, 2.4375f, 1.f, -2.4375f, 1.f, 0.f},
    {0.f, 0.f, 1.625f, 1.625f, -1.625f, 1.625f, 0.f, 1.625f, 1.625f}};
__device__ const int c_n[3]       = {9, 8, 9};
__device__ const int c_C[3]       = {67, 76, 67};
__device__ const int c_mapbase[3] = {0, 3, 15};

// z = br*4 + half*2 + quarter: 32 outputs per thread (avoids AGPR round-trips)
__global__ __launch_bounds__(256) void kv_kernel(float* __restrict__ ws,
                                                 const float* __restrict__ out)
{
    const int px = blockIdx.x * 256 + threadIdx.x;
    const int b = blockIdx.y;
    const int br = blockIdx.z >> 2, half = (blockIdx.z >> 1) & 1, qt = blockIdx.z & 1;
    const int h = px >> 7, w = px & 127;
    const float* feats = ws + OFF_FEATS + ((size_t)b * 192 + br * 64) * HW;
    const float* maps  = out + ((size_t)b * 26 + c_mapbase[br]) * HW;
    const float* wtb   = ws + OFF_KVWT + (size_t)br * 79872 + half * 64 + qt * 32;
    const float* kvb   = ws + OFF_KVB + br * 128 + half * 64 + qt * 32;
    const int n = c_n[br], C = c_C[br];
    float acc[32];
    #pragma unroll
    for (int o = 0; o < 32; ++o) acc[o] = kvb[o];
    for (int p = 0; p < n; ++p) {
        float ox = c_ox[br][p], oy = c_oy[br][p];
        float fox = floorf(ox), foy = floorf(oy);
        int ix = (int)fox, iy = (int)foy;
        float dx = ox - fox, dy = oy - foy;
        int x0 = w + ix, y0 = h + iy;
        float w00 = (1.f - dx) * (1.f - dy), w10 = dx * (1.f - dy);
        float w01 = (1.f - dx) * dy,         w11 = dx * dy;
        bool vx0 = (unsigned)x0 < 128u, vx1 = (unsigned)(x0 + 1) < 128u;
        bool vy0 = (unsigned)y0 < 128u, vy1 = (unsigned)(y0 + 1) < 128u;
        float m00 = (vx0 && vy0) ? w00 : 0.f, m10 = (vx1 && vy0) ? w10 : 0.f;
        float m01 = (vx0 && vy1) ? w01 : 0.f, m11 = (vx1 && vy1) ? w11 : 0.f;
        int cx0 = min(max(x0, 0), 127), cx1 = min(max(x0 + 1, 0), 127);
        int cy0 = min(max(y0, 0), 127), cy1 = min(max(y0 + 1, 0), 127);
        int a00 = cy0 * WIMG + cx0, a10 = cy0 * WIMG + cx1;
        int a01 = cy1 * WIMG + cx0, a11 = cy1 * WIMG + cx1;
        for (int c = 0; c < C; ++c) {
            const float* F = (c < 64) ? (feats + c * HW) : (maps + (c - 64) * HW);
            float S = m00 * F[a00] + m10 * F[a10] + m01 * F[a01] + m11 * F[a11];
            const float* wr = wtb + (c * n + p) * 128;
            #pragma unroll
            for (int o = 0; o < 32; ++o) acc[o] = fmaf(wr[o], S, acc[o]);
        }
        float gx = (w + 0.5f + ox) * (1.0f / 128.0f);
        float gy = (h + 0.5f + oy) * (1.0f / 128.0f);
        const float* wrx = wtb + (C * n + p) * 128;
        const float* wry = wtb + ((C + 1) * n + p) * 128;
        #pragma unroll
        for (int o = 0; o < 32; ++o) acc[o] = fmaf(wrx[o], gx, acc[o]);
        #pragma unroll
        for (int o = 0; o < 32; ++o) acc[o] = fmaf(wry[o], gy, acc[o]);
    }
    float* kv = ws + OFF_KV;
    const int ob = (br * 4 + b) * 128 + half * 64 + qt * 32;
    #pragma unroll
    for (int o = 0; o < 32; ++o)
        kv[(size_t)(ob + o) * HW + px] = fmaxf(acc[o], 0.f);
}

// ------------------- attention (softmax over 3) + predict -------------------
__global__ __launch_bounds__(256) void attn_pred_kernel(
    const float* __restrict__ base, float* __restrict__ ws,
    const float* __restrict__ p2w, const float* __restrict__ p2b,
    float* __restrict__ out)
{
    const int px = blockIdx.x * 256 + threadIdx.x;
    const int b = blockIdx.y;
    const float* q  = ws + OFF_Q + (size_t)b * 64 * HW + px;
    const float* kv = ws + OFF_KV;
    float aw[4][3];
    #pragma unroll
    for (int nh = 0; nh < 4; ++nh) {
        float l0 = 0.f, l1 = 0.f, l2 = 0.f;
        #pragma unroll
        for (int ko = 0; ko < 16; ++ko) {
            float qv = q[(nh * 16 + ko) * HW];
            l0 = fmaf(qv, kv[(size_t)((0 * 4 + b) * 128 + nh * 16 + ko) * HW + px], l0);
            l1 = fmaf(qv, kv[(size_t)((1 * 4 + b) * 128 + nh * 16 + ko) * HW + px], l1);
            l2 = fmaf(qv, kv[(size_t)((2 * 4 + b) * 128 + nh * 16 + ko) * HW + px], l2);
        }
        float m = fmaxf(l0, fmaxf(l1, l2));
        float e0 = expf(l0 - m), e1 = expf(l1 - m), e2 = expf(l2 - m);
        float inv = 1.f / (e0 + e1 + e2);
        aw[nh][0] = e0 * inv; aw[nh][1] = e1 * inv; aw[nh][2] = e2 * inv;
    }
    const float* p1wt = ws + OFF_P1WT;
    const float* p1b  = ws + OFF_P1B;
    const float* inb  = base + (size_t)b * 256 * HW + px;
    #pragma unroll
    for (int nh = 0; nh < 4; ++nh) {
        float attn[16];
        #pragma unroll
        for (int va = 0; va < 16; ++va) {
            attn[va] =
                aw[nh][0] * kv[(size_t)((0 * 4 + b) * 128 + 64 + nh * 16 + va) * HW + px] +
                aw[nh][1] * kv[(size_t)((1 * 4 + b) * 128 + 64 + nh * 16 + va) * HW + px] +
                aw[nh][2] * kv[(size_t)((2 * 4 + b) * 128 + 64 + nh * 16 + va) * HW + px];
        }
        float acc[64];
        #pragma unroll
        for (int j = 0; j < 64; ++j) acc[j] = p1b[nh * 64 + j];
        #pragma unroll 4
        for (int c = 0; c < 256; ++c) {
            float v = inb[c * HW];
            const float* wr = p1wt + c * 256 + nh * 64;
            #pragma unroll
            for (int j = 0; j < 64; ++j) acc[j] = fmaf(wr[j], v, acc[j]);
        }
        #pragma unroll
        for (int va = 0; va < 16; ++va) {
            const float* wr = p1wt + (256 + va) * 256 + nh * 64;
            #pragma unroll
            for (int j = 0; j < 64; ++j) acc[j] = fmaf(wr[j], attn[va], acc[j]);
        }
        float o0 = p2b[nh * 2 + 0], o1 = p2b[nh * 2 + 1];
        #pragma unroll
        for (int j = 0; j < 64; ++j) {
            float hj = fmaxf(acc[j], 0.f);
            o0 = fmaf(p2w[(nh * 2 + 0) * 64 + j], hj, o0);
            o1 = fmaf(p2w[(nh * 2 + 1) * 64 + j], hj, o1);
        }
        out[((size_t)b * 26 + 18 + nh * 2) * HW + px] = o0;
        out[((size_t)b * 26 + 19 + nh * 2) * HW + px] = o1;
    }
}

// ---------------------------------------------------------------------------
extern "C" void kernel_launch(void* const* d_in, const int* in_sizes, int n_in,
                              void* d_out, int out_size, void* d_ws, size_t ws_size,
                              hipStream_t stream) {
    (void)in_sizes; (void)n_in; (void)out_size; (void)ws_size;
    float* ws  = (float*)d_ws;
    float* out = (float*)d_out;
    const float* base = (const float*)d_in[0];
    P53 ptrs;
    for (int i = 0; i < 53; ++i) ptrs.p[i] = (const float*)d_in[i];

    prep_kernel<<<3044, 256, 0, stream>>>(ptrs, ws);
    // MFMA conv: grid (xhalf, row, batch); all 3 branches fused (M=192)
    conv_base_mfma<<<dim3(2, 128, 4), 256, 0, stream>>>(
        base, (const ushortT*)(ws + OFF_CWT), ws + OFF_CB, ws + OFF_FEATS);
    conv_head_kernel<<<dim3(8, 8, 4), 256, 0, stream>>>(ws + OFF_FEATS, ws,
                                                        (const float*)d_in[6],
                                                        (const float*)d_in[12],
                                                        (const float*)d_in[18], out);
    q_kernel<<<dim3(64, 4), 256, 0, stream>>>(base, ws);
    kv_kernel<<<dim3(64, 4, 12), 256, 0, stream>>>(ws, out);
    attn_pred_kernel<<<dim3(64, 4), 256, 0, stream>>>(base, ws, (const float*)d_in[51],
                                                      (const float*)d_in[52], out);
}

// Round 3
// 1015.016 us; speedup vs baseline: 2.9173x; 1.7993x over previous
//
#include <hip/hip_runtime.h>
#include <hip/hip_bf16.h>
#include <math.h>

// ---------------------------------------------------------------------------
// HydraFusionHead: B=4, IN_CH=256, HEAD_CH=64, H=W=128, NH=4, KEY=VAL=16
// conv_base: bf16 MFMA implicit GEMM (M=192, K=2304 tap-major).
// attn+predict: bf16 MFMA GEMM M=256 (4 heads x 64), K=320 (base 256 + 4x16
//   per-head att slices, rows zeroed off-head), fused softmax-attention
//   staging + p2 epilogue with shfl reduction.
// q: bf16 MFMA GEMM M=64, K=256.
// ---------------------------------------------------------------------------

#define HW 16384
#define WIMG 128

typedef unsigned short ushortT;
typedef __attribute__((ext_vector_type(8))) short short8;
typedef __attribute__((ext_vector_type(4))) float floatx4;

// ws layout (float offsets)
constexpr size_t OFF_FEATS = 0;                   // [4][192][HW]
constexpr size_t OFF_Q     = 12582912;            // [4][64][HW]
constexpr size_t OFF_KV    = 16777216;            // [3][4][128][HW]
constexpr size_t OFF_CWT   = 41943040;            // bf16 wA [9][32][192][8] (442368 us)
constexpr size_t OFF_CB    = OFF_CWT + 442368;    // [3][64] fp32
constexpr size_t OFF_HWT   = OFF_CB + 192;        // [3][64][9][12] fp32, zero-padded
constexpr size_t OFF_QWT   = OFF_HWT + 20736;     // bf16 wQ [8][4][64][8] (16384 us)
constexpr size_t OFF_QB    = OFF_QWT + 16384;     // [64]
constexpr size_t OFF_KVWT  = OFF_QB + 64;         // [3][624][128] fp32
constexpr size_t OFF_KVB   = OFF_KVWT + 239616;   // [3][128]
constexpr size_t OFF_P1WT  = OFF_KVB + 384;       // bf16 wP1 [10][4][256][8] (81920 us)
constexpr size_t OFF_P1B   = OFF_P1WT + 81920;    // [256]

struct P53 { const float* p[53]; };

__device__ inline ushortT f2bf(float f) {
    unsigned u = __float_as_uint(f);
    unsigned r = (u + 0x7FFFu + ((u >> 16) & 1u)) >> 16;
    return (ushortT)r;
}
__device__ inline unsigned packbf(float a, float b) {
    return (unsigned)f2bf(a) | ((unsigned)f2bf(b) << 16);
}

// --------------------------- prep: fold BN + transpose ----------------------
__global__ __launch_bounds__(256) void prep_kernel(P53 ptrs, float* __restrict__ ws) {
    int i = blockIdx.x * 256 + threadIdx.x;
    const float* const* p = ptrs.p;
    // bf16 conv weights wA[tap][g(32)][M(192)][j(8)], M = br*64+oc, ic = g*8+j
    if (i < 442368) {
        int tap = i / 49152, r = i % 49152;
        int g = r / 1536, r2 = r % 1536;
        int M = r2 >> 3, j = r2 & 7;
        int br = M >> 6, oc = M & 63, ic = g * 8 + j;
        float v = p[1 + 6 * br][(oc * 256 + ic) * 9 + tap] * p[3 + 6 * br][oc];
        ((ushortT*)(ws + OFF_CWT))[i] = f2bf(v);
        return;
    }
    i -= 442368;
    if (i < 192) {  // conv bias: b*s + t
        int br = i >> 6, oc = i & 63;
        ws[OFF_CB + i] = p[2 + 6 * br][oc] * p[3 + 6 * br][oc] + p[4 + 6 * br][oc];
        return;
    }
    i -= 192;
    if (i < 20736) {  // head conv weights [br][c64][k9][12] zero-padded
        int j = i % 12, k = (i / 12) % 9, c = (i / 108) % 64, br = i / 6912;
        int cnt = (br == 1) ? 12 : 3;
        const float* hw = (br == 0) ? p[5] : (br == 1) ? p[11] : p[17];
        ws[OFF_HWT + i] = (j < cnt) ? hw[(j * 64 + c) * 9 + k] : 0.f;
        return;
    }
    i -= 20736;
    if (i < 16384) {  // bf16 wQ[kk8][sub4][m64][j8]
        int j = i & 7, m = (i >> 3) & 63, sg = i >> 9;
        int k = (sg >> 2) * 32 + (sg & 3) * 8 + j;
        ((ushortT*)(ws + OFF_QWT))[i] = f2bf(p[19][m * 256 + k] * p[21][m]);
        return;
    }
    i -= 16384;
    if (i < 64) { ws[OFF_QB + i] = p[20][i] * p[21][i] + p[22][i]; return; }
    i -= 64;
    if (i < 239616) {  // kv_wt [3][624][128]
        int o = i & 127, cp = (i >> 7) % 624, br = i / 79872;
        int Cn = (br == 1) ? 624 : 621;
        float v = 0.f;
        if (cp < Cn) {
            if (o < 64) v = p[23 + 8 * br][o * Cn + cp] * p[25 + 8 * br][o];
            else { int o2 = o - 64; v = p[27 + 8 * br][o2 * Cn + cp] * p[29 + 8 * br][o2]; }
        }
        ws[OFF_KVWT + i] = v; return;
    }
    i -= 239616;
    if (i < 384) {
        int br = i / 128, o = i % 128;
        float v = (o < 64)
            ? p[24 + 8 * br][o] * p[25 + 8 * br][o] + p[26 + 8 * br][o]
            : p[28 + 8 * br][o - 64] * p[29 + 8 * br][o - 64] + p[30 + 8 * br][o - 64];
        ws[OFF_KVB + i] = v; return;
    }
    i -= 384;
    if (i < 81920) {  // bf16 wP1[kk10][sub4][M256][j8], K=320 extended
        int j = i & 7, M = (i >> 3) & 255, sg = i >> 11;
        int k = (sg >> 2) * 32 + (sg & 3) * 8 + j;
        int nh = M >> 6, oc = M & 63;
        float sc = p[49][nh * 64 + oc];
        float v;
        if (k < 256) v = p[47][(nh * 64 + oc) * 272 + k] * sc;
        else {
            int k2 = k - 256, nh2 = k2 >> 4, va = k2 & 15;
            v = (nh2 == nh) ? p[47][(nh * 64 + oc) * 272 + 256 + va] * sc : 0.f;
        }
        ((ushortT*)(ws + OFF_P1WT))[i] = f2bf(v);
        return;
    }
    i -= 81920;
    if (i < 256) { ws[OFF_P1B + i] = p[48][i] * p[49][i] + p[50][i]; return; }
}

// ------------- conv3x3 base(256) -> 192 feats via bf16 MFMA -----------------
__global__ __launch_bounds__(256) void conv_base_mfma(
    const float* __restrict__ base, const ushortT* __restrict__ wA,
    const float* __restrict__ cb, float* __restrict__ feats)
{
    const int wv = threadIdx.x >> 6, lane = threadIdx.x & 63;
    const int sub = lane >> 4, ln = lane & 15;
    const int xh = blockIdx.x, h = blockIdx.y, b = blockIdx.z;
    __shared__ __align__(16) ushortT sbuf[8 * 3 * 66 * 8];

    floatx4 acc[3][4];
    #pragma unroll
    for (int mt = 0; mt < 3; ++mt)
        #pragma unroll
        for (int nt = 0; nt < 4; ++nt)
            #pragma unroll
            for (int r = 0; r < 4; ++r) acc[mt][nt][r] = 0.f;

    const float* inb = base + (size_t)b * 256 * HW;
    const int icp = threadIdx.x & 3;

    for (int s = 0; s < 4; ++s) {
        const int icbase = s * 64;
        __syncthreads();
        for (int it = 0; it < 25; ++it) {
            int idx = threadIdx.x + it * 256;
            if (idx < 6336) {
                int elem = idx >> 2;
                int c = elem % 66, t2 = elem / 66;
                int r = t2 % 3, icg = t2 / 3;
                int gh = h + r - 1, gw = xh * 64 + c - 1;
                int ic = icbase + icg * 8 + icp * 2;
                float v0 = 0.f, v1 = 0.f;
                if ((unsigned)gh < 128u && (unsigned)gw < 128u) {
                    const float* pp = inb + (size_t)ic * HW + gh * WIMG + gw;
                    v0 = pp[0]; v1 = pp[HW];
                }
                ((unsigned*)sbuf)[idx] = packbf(v0, v1);
            }
        }
        __syncthreads();
        #pragma unroll
        for (int tap = 0; tap < 9; ++tap) {
            const int ky = tap / 3, kx = tap % 3;
            #pragma unroll
            for (int icc = 0; icc < 2; ++icc) {
                const int icgl = icc * 4 + sub;
                short8 Bf[4];
                #pragma unroll
                for (int nt = 0; nt < 4; ++nt) {
                    int c = nt * 16 + ln + kx;
                    int elem = (icgl * 3 + ky) * 66 + c;
                    Bf[nt] = *(const short8*)(sbuf + elem * 8);
                }
                const int g = s * 8 + icc * 4 + sub;
                short8 Af[3];
                #pragma unroll
                for (int mt = 0; mt < 3; ++mt) {
                    int m = wv * 48 + mt * 16 + ln;
                    Af[mt] = *(const short8*)(wA + (((size_t)tap * 32 + g) * 192 + m) * 8);
                }
                #pragma unroll
                for (int mt = 0; mt < 3; ++mt)
                    #pragma unroll
                    for (int nt = 0; nt < 4; ++nt)
                        acc[mt][nt] = __builtin_amdgcn_mfma_f32_16x16x32_bf16(
                            Af[mt], Bf[nt], acc[mt][nt], 0, 0, 0);
            }
        }
    }
    #pragma unroll
    for (int mt = 0; mt < 3; ++mt) {
        #pragma unroll
        for (int nt = 0; nt < 4; ++nt) {
            #pragma unroll
            for (int r = 0; r < 4; ++r) {
                int Mi = wv * 48 + mt * 16 + sub * 4 + r;
                int px = xh * 64 + nt * 16 + ln;
                float v = acc[mt][nt][r] + cb[Mi];
                feats[((size_t)b * 192 + Mi) * HW + h * WIMG + px] = fmaxf(v, 0.f);
            }
        }
    }
}

// ---------------- head 3x3 convs (64 -> 3/12/3) -> d_out ch 0..17 -----------
// branch-split: grid z = b*3+br, weights zero-padded to 12 outputs
__global__ __launch_bounds__(256) void conv_head_kernel(
    const float* __restrict__ feats, const float* __restrict__ hwt_all,
    const float* __restrict__ chb, const float* __restrict__ ohb,
    const float* __restrict__ fhb, float* __restrict__ out)
{
    const int tx = threadIdx.x & 15, ty = threadIdx.x >> 4;
    const int w0 = blockIdx.x << 4, h0 = blockIdx.y << 4;
    const int br = blockIdx.z % 3, b = blockIdx.z / 3;
    const int cnt = (br == 1) ? 12 : 3;
    const int mapb = (br == 0) ? 0 : (br == 1) ? 3 : 15;
    const float* bias = (br == 0) ? chb : (br == 1) ? ohb : fhb;
    const float* hwt = hwt_all + br * 6912;
    __shared__ float tile[4][18][18];
    float acc[12];
    #pragma unroll
    for (int j = 0; j < 12; ++j) acc[j] = (j < cnt) ? bias[j] : 0.f;
    const float* fb = feats + ((size_t)b * 192 + br * 64) * HW;
    for (int c0 = 0; c0 < 64; c0 += 4) {
        __syncthreads();
        for (int i = threadIdx.x; i < 1296; i += 256) {
            int cc = i / 324, r = (i % 324) / 18, col = i % 18;
            int gh = h0 + r - 1, gw = w0 + col - 1;
            float v = 0.f;
            if ((unsigned)gh < 128u && (unsigned)gw < 128u)
                v = fb[(c0 + cc) * HW + gh * WIMG + gw];
            tile[cc][r][col] = v;
        }
        __syncthreads();
        #pragma unroll
        for (int cc = 0; cc < 4; ++cc) {
            float in[9];
            #pragma unroll
            for (int ky = 0; ky < 3; ++ky)
                #pragma unroll
                for (int kx = 0; kx < 3; ++kx)
                    in[ky * 3 + kx] = tile[cc][ty + ky][tx + kx];
            const float* wr = hwt + (c0 + cc) * 108;
            #pragma unroll
            for (int k = 0; k < 9; ++k) {
                #pragma unroll
                for (int j = 0; j < 12; ++j)
                    acc[j] = fmaf(wr[k * 12 + j], in[k], acc[j]);
            }
        }
    }
    float* ob = out + ((size_t)b * 26 + mapb) * HW + (h0 + ty) * WIMG + (w0 + tx);
    #pragma unroll
    for (int j = 0; j < 12; ++j)
        if (j < cnt) ob[j * HW] = acc[j];
}

// ----------------------------- q via bf16 MFMA ------------------------------
__global__ __launch_bounds__(256) void q_mfma(const float* __restrict__ base,
                                              float* __restrict__ ws)
{
    const int wv = threadIdx.x >> 6, lane = threadIdx.x & 63;
    const int sub = lane >> 4, ln = lane & 15;
    const int px0 = blockIdx.x * 64, b = blockIdx.y;
    const ushortT* wQ = (const ushortT*)(ws + OFF_QWT);
    const float* qb = ws + OFF_QB;
    __shared__ __align__(16) ushortT xb[32 * 64 * 8];  // 32 KB

    const int mypx = threadIdx.x & 63, q4 = threadIdx.x >> 6;
    const float* inb = base + (size_t)b * 256 * HW + px0 + mypx;
    #pragma unroll
    for (int icp = 0; icp < 32; ++icp) {
        int ic = q4 * 64 + icp * 2;
        float v0 = inb[(size_t)ic * HW], v1 = inb[(size_t)(ic + 1) * HW];
        int g = ic >> 3, wo = (ic & 7) >> 1;
        ((unsigned*)xb)[(g * 64 + mypx) * 4 + wo] = packbf(v0, v1);
    }
    __syncthreads();

    floatx4 acc[4];
    #pragma unroll
    for (int mt = 0; mt < 4; ++mt)
        #pragma unroll
        for (int r = 0; r < 4; ++r) acc[mt][r] = 0.f;
    #pragma unroll
    for (int kk = 0; kk < 8; ++kk) {
        short8 Bf = *(const short8*)(xb + (((kk * 4 + sub) * 64) + wv * 16 + ln) * 8);
        #pragma unroll
        for (int mt = 0; mt < 4; ++mt) {
            short8 Af = *(const short8*)(wQ + (((kk * 4 + sub) * 64) + mt * 16 + ln) * 8);
            acc[mt] = __builtin_amdgcn_mfma_f32_16x16x32_bf16(Af, Bf, acc[mt], 0, 0, 0);
        }
    }
    float* q = ws + OFF_Q + (size_t)b * 64 * HW;
    #pragma unroll
    for (int mt = 0; mt < 4; ++mt)
        #pragma unroll
        for (int r = 0; r < 4; ++r) {
            int Mi = mt * 16 + sub * 4 + r;
            int px = px0 + wv * 16 + ln;
            q[(size_t)Mi * HW + px] = fmaxf(acc[mt][r] + qb[Mi], 0.f);
        }
}

// ------------------ fused sampling + per-head 1x1 K/V conv ------------------
__device__ const float c_ox[3][9] = {
    {-1.f, 0.f, 1.f, -1.f, 0.f, 1.f, -1.f, 0.f, 1.f},
    {-1.f, 2.4375f, -1.f, -2.4375f, 1.f, 2.4375f, 1.f, -2.4375f, 0.f},
    {-1.625f, -1.625f, -1.625f, 0.f, -1.625f, 1.625f, 0.f, -1.625f, 0.f}};
__device__ const float c_oy[3][9] = {
    {-1.f, -1.f, -1.f, 0.f, 0.f, 0.f, 1.f, 1.f, 1.f},
    {2.4375f, -1.f, -2.4375f, -1.f, 2.4375f, 1.f, -2.4375f, 1.f, 0.f},
    {0.f, 0.f, 1.625f, 1.625f, -1.625f, 1.625f, 0.f, 1.625f, 1.625f}};
__device__ const int c_n[3]       = {9, 8, 9};
__device__ const int c_C[3]       = {67, 76, 67};
__device__ const int c_mapbase[3] = {0, 3, 15};

__global__ __launch_bounds__(256) void kv_kernel(float* __restrict__ ws,
                                                 const float* __restrict__ out)
{
    const int px = blockIdx.x * 256 + threadIdx.x;
    const int b = blockIdx.y;
    const int br = blockIdx.z >> 2, half = (blockIdx.z >> 1) & 1, qt = blockIdx.z & 1;
    const int h = px >> 7, w = px & 127;
    const float* feats = ws + OFF_FEATS + ((size_t)b * 192 + br * 64) * HW;
    const float* maps  = out + ((size_t)b * 26 + c_mapbase[br]) * HW;
    const float* wtb   = ws + OFF_KVWT + (size_t)br * 79872 + half * 64 + qt * 32;
    const float* kvb   = ws + OFF_KVB + br * 128 + half * 64 + qt * 32;
    const int n = c_n[br], C = c_C[br];
    float acc[32];
    #pragma unroll
    for (int o = 0; o < 32; ++o) acc[o] = kvb[o];
    for (int p = 0; p < n; ++p) {
        float ox = c_ox[br][p], oy = c_oy[br][p];
        float fox = floorf(ox), foy = floorf(oy);
        int ix = (int)fox, iy = (int)foy;
        float dx = ox - fox, dy = oy - foy;
        int x0 = w + ix, y0 = h + iy;
        float w00 = (1.f - dx) * (1.f - dy), w10 = dx * (1.f - dy);
        float w01 = (1.f - dx) * dy,         w11 = dx * dy;
        bool vx0 = (unsigned)x0 < 128u, vx1 = (unsigned)(x0 + 1) < 128u;
        bool vy0 = (unsigned)y0 < 128u, vy1 = (unsigned)(y0 + 1) < 128u;
        float m00 = (vx0 && vy0) ? w00 : 0.f, m10 = (vx1 && vy0) ? w10 : 0.f;
        float m01 = (vx0 && vy1) ? w01 : 0.f, m11 = (vx1 && vy1) ? w11 : 0.f;
        int cx0 = min(max(x0, 0), 127), cx1 = min(max(x0 + 1, 0), 127);
        int cy0 = min(max(y0, 0), 127), cy1 = min(max(y0 + 1, 0), 127);
        int a00 = cy0 * WIMG + cx0, a10 = cy0 * WIMG + cx1;
        int a01 = cy1 * WIMG + cx0, a11 = cy1 * WIMG + cx1;
        for (int c = 0; c < C; ++c) {
            const float* F = (c < 64) ? (feats + c * HW) : (maps + (c - 64) * HW);
            float S = m00 * F[a00] + m10 * F[a10] + m01 * F[a01] + m11 * F[a11];
            const float* wr = wtb + (c * n + p) * 128;
            #pragma unroll
            for (int o = 0; o < 32; ++o) acc[o] = fmaf(wr[o], S, acc[o]);
        }
        float gx = (w + 0.5f + ox) * (1.0f / 128.0f);
        float gy = (h + 0.5f + oy) * (1.0f / 128.0f);
        const float* wrx = wtb + (C * n + p) * 128;
        const float* wry = wtb + ((C + 1) * n + p) * 128;
        #pragma unroll
        for (int o = 0; o < 32; ++o) acc[o] = fmaf(wrx[o], gx, acc[o]);
        #pragma unroll
        for (int o = 0; o < 32; ++o) acc[o] = fmaf(wry[o], gy, acc[o]);
    }
    float* kv = ws + OFF_KV;
    const int ob = (br * 4 + b) * 128 + half * 64 + qt * 32;
    #pragma unroll
    for (int o = 0; o < 32; ++o)
        kv[(size_t)(ob + o) * HW + px] = fmaxf(acc[o], 0.f);
}

// ---------- attention softmax + p1(MFMA, K=320) + relu + p2 -> out ----------
__global__ __launch_bounds__(256) void attn_pred_mfma(
    const float* __restrict__ base, float* __restrict__ ws,
    const float* __restrict__ p2w, const float* __restrict__ p2b,
    float* __restrict__ out)
{
    const int wv = threadIdx.x >> 6, lane = threadIdx.x & 63;
    const int sub = lane >> 4, ln = lane & 15;
    const int px0 = blockIdx.x * 64, b = blockIdx.y;
    const ushortT* wP1 = (const ushortT*)(ws + OFF_P1WT);
    const float* p1b = ws + OFF_P1B;
    __shared__ __align__(16) ushortT xbuf[40 * 64 * 8];  // 40 KB

    const int mypx = threadIdx.x & 63, nh = threadIdx.x >> 6;
    const int gpx = px0 + mypx;
    // stage base channels nh*64..nh*64+63 -> groups 0..31
    const float* inb = base + (size_t)b * 256 * HW + gpx;
    #pragma unroll
    for (int icp = 0; icp < 32; ++icp) {
        int ic = nh * 64 + icp * 2;
        float v0 = inb[(size_t)ic * HW], v1 = inb[(size_t)(ic + 1) * HW];
        int g = ic >> 3, wo = (ic & 7) >> 1;
        ((unsigned*)xbuf)[(g * 64 + mypx) * 4 + wo] = packbf(v0, v1);
    }
    // attention for (px, nh): logits over 3 branches, softmax, att -> groups 32..39
    {
        const float* q  = ws + OFF_Q + ((size_t)b * 64 + nh * 16) * HW + gpx;
        const float* kv = ws + OFF_KV;
        float l[3];
        #pragma unroll
        for (int br = 0; br < 3; ++br) {
            float s = 0.f;
            #pragma unroll
            for (int ko = 0; ko < 16; ++ko)
                s = fmaf(q[(size_t)ko * HW],
                         kv[(size_t)((br * 4 + b) * 128 + nh * 16 + ko) * HW + gpx], s);
            l[br] = s;
        }
        float m = fmaxf(l[0], fmaxf(l[1], l[2]));
        float e0 = __expf(l[0] - m), e1 = __expf(l[1] - m), e2 = __expf(l[2] - m);
        float inv = 1.f / (e0 + e1 + e2);
        float aw0 = e0 * inv, aw1 = e1 * inv, aw2 = e2 * inv;
        #pragma unroll
        for (int vap = 0; vap < 8; ++vap) {
            int va0 = vap * 2, va1 = vap * 2 + 1;
            float a0 =
                aw0 * kv[(size_t)((0 * 4 + b) * 128 + 64 + nh * 16 + va0) * HW + gpx] +
                aw1 * kv[(size_t)((1 * 4 + b) * 128 + 64 + nh * 16 + va0) * HW + gpx] +
                aw2 * kv[(size_t)((2 * 4 + b) * 128 + 64 + nh * 16 + va0) * HW + gpx];
            float a1 =
                aw0 * kv[(size_t)((0 * 4 + b) * 128 + 64 + nh * 16 + va1) * HW + gpx] +
                aw1 * kv[(size_t)((1 * 4 + b) * 128 + 64 + nh * 16 + va1) * HW + gpx] +
                aw2 * kv[(size_t)((2 * 4 + b) * 128 + 64 + nh * 16 + va1) * HW + gpx];
            int g = 32 + nh * 2 + (vap >> 2), wo = vap & 3;
            ((unsigned*)xbuf)[(g * 64 + mypx) * 4 + wo] = packbf(a0, a1);
        }
    }
    __syncthreads();

    // GEMM: M=256 (wave wv = head wv, 64 rows), N=64 px, K=320
    floatx4 acc[4][4];
    #pragma unroll
    for (int mt = 0; mt < 4; ++mt)
        #pragma unroll
        for (int nt = 0; nt < 4; ++nt)
            #pragma unroll
            for (int r = 0; r < 4; ++r) acc[mt][nt][r] = 0.f;
    #pragma unroll
    for (int kk = 0; kk < 10; ++kk) {
        short8 Bf[4];
        #pragma unroll
        for (int nt = 0; nt < 4; ++nt)
            Bf[nt] = *(const short8*)(xbuf + (((kk * 4 + sub) * 64) + nt * 16 + ln) * 8);
        #pragma unroll
        for (int mt = 0; mt < 4; ++mt) {
            short8 Af = *(const short8*)(wP1 + (((size_t)(kk * 4 + sub) * 256) + wv * 64 + mt * 16 + ln) * 8);
            #pragma unroll
            for (int nt = 0; nt < 4; ++nt)
                acc[mt][nt] = __builtin_amdgcn_mfma_f32_16x16x32_bf16(Af, Bf[nt], acc[mt][nt], 0, 0, 0);
        }
    }

    // epilogue: bias+relu, p2 (2 outputs per head), reduce across sub via shfl
    float po0[4] = {0.f, 0.f, 0.f, 0.f}, po1[4] = {0.f, 0.f, 0.f, 0.f};
    #pragma unroll
    for (int mt = 0; mt < 4; ++mt) {
        #pragma unroll
        for (int r = 0; r < 4; ++r) {
            int oc = mt * 16 + sub * 4 + r;
            float bias = p1b[wv * 64 + oc];
            float w0 = p2w[(wv * 2 + 0) * 64 + oc];
            float w1 = p2w[(wv * 2 + 1) * 64 + oc];
            #pragma unroll
            for (int nt = 0; nt < 4; ++nt) {
                float hv = fmaxf(acc[mt][nt][r] + bias, 0.f);
                po0[nt] = fmaf(w0, hv, po0[nt]);
                po1[nt] = fmaf(w1, hv, po1[nt]);
            }
        }
    }
    #pragma unroll
    for (int nt = 0; nt < 4; ++nt) {
        po0[nt] += __shfl_xor(po0[nt], 16);
        po0[nt] += __shfl_xor(po0[nt], 32);
        po1[nt] += __shfl_xor(po1[nt], 16);
        po1[nt] += __shfl_xor(po1[nt], 32);
    }
    if (sub == 0) {
        #pragma unroll
        for (int nt = 0; nt < 4; ++nt) {
            int px = px0 + nt * 16 + ln;
            out[((size_t)b * 26 + 18 + wv * 2 + 0) * HW + px] = po0[nt] + p2b[wv * 2 + 0];
            out[((size_t)b * 26 + 18 + wv * 2 + 1) * HW + px] = po1[nt] + p2b[wv * 2 + 1];
        }
    }
}

// ---------------------------------------------------------------------------
extern "C" void kernel_launch(void* const* d_in, const int* in_sizes, int n_in,
                              void* d_out, int out_size, void* d_ws, size_t ws_size,
                              hipStream_t stream) {
    (void)in_sizes; (void)n_in; (void)out_size; (void)ws_size;
    float* ws  = (float*)d_ws;
    float* out = (float*)d_out;
    const float* base = (const float*)d_in[0];
    P53 ptrs;
    for (int i = 0; i < 53; ++i) ptrs.p[i] = (const float*)d_in[i];

    prep_kernel<<<3133, 256, 0, stream>>>(ptrs, ws);
    conv_base_mfma<<<dim3(2, 128, 4), 256, 0, stream>>>(
        base, (const ushortT*)(ws + OFF_CWT), ws + OFF_CB, ws + OFF_FEATS);
    conv_head_kernel<<<dim3(8, 8, 12), 256, 0, stream>>>(ws + OFF_FEATS, ws + OFF_HWT,
                                                         (const float*)d_in[6],
                                                         (const float*)d_in[12],
                                                         (const float*)d_in[18], out);
    q_mfma<<<dim3(256, 4), 256, 0, stream>>>(base, ws);
    kv_kernel<<<dim3(64, 4, 12), 256, 0, stream>>>(ws, out);
    attn_pred_mfma<<<dim3(256, 4), 256, 0, stream>>>(base, ws, (const float*)d_in[51],
                                                     (const float*)d_in[52], out);
}

// Round 4
// 708.276 us; speedup vs baseline: 4.1807x; 1.4331x over previous
//
#include <hip/hip_runtime.h>
#include <hip/hip_bf16.h>
#include <math.h>

// ---------------------------------------------------------------------------
// HydraFusionHead: B=4, IN_CH=256, HEAD_CH=64, H=W=128, NH=4, KEY=VAL=16
// conv_base: bf16 MFMA implicit GEMM (M=192, K=2304 tap-major).
// kv: sampling+1x1 collapsed into sparse-tap convs (taps 9/16/25) run as
//     bf16 MFMA implicit GEMM, M=128 (k+v), N=64 px; geo terms are affine
//     in pixel coords -> epilogue GA*x+GB*y+GC. BN folded everywhere.
// attn+predict / q: bf16 MFMA GEMMs (unchanged from round 3).
// ---------------------------------------------------------------------------

#define HW 16384
#define WIMG 128

typedef unsigned short ushortT;
typedef __attribute__((ext_vector_type(8))) short short8;
typedef __attribute__((ext_vector_type(4))) float floatx4;

// ws layout (float offsets)
constexpr size_t OFF_FEATS = 0;                   // [4][192][HW]
constexpr size_t OFF_Q     = 12582912;            // [4][64][HW]
constexpr size_t OFF_KV    = 16777216;            // [3][4][128][HW]
constexpr size_t OFF_CWT   = 41943040;            // bf16 wA [9][32][192][8] (442368 us)
constexpr size_t OFF_CB    = OFF_CWT + 442368;    // [3][64] fp32
constexpr size_t OFF_HWT   = OFF_CB + 192;        // [3][64][9][12] fp32 zero-padded
constexpr size_t OFF_QWT   = OFF_HWT + 20736;     // bf16 wQ (16384 us)
constexpr size_t OFF_QB    = OFF_QWT + 16384;     // [64]
constexpr size_t OFF_KVW   = OFF_QB + 64;         // bf16 W_eff [472 units][128][8] (483328 us)
constexpr size_t OFF_GEO   = OFF_KVW + 241664;    // fp32 [3][3][128] (GA,GB,GC)
constexpr size_t OFF_P1WT  = OFF_GEO + 1152;      // bf16 wP1 (81920 us)
constexpr size_t OFF_P1B   = OFF_P1WT + 81920;    // [256]

struct P53 { const float* p[53]; };

__device__ inline ushortT f2bf(float f) {
    unsigned u = __float_as_uint(f);
    unsigned r = (u + 0x7FFFu + ((u >> 16) & 1u)) >> 16;
    return (ushortT)r;
}
__device__ inline unsigned packbf(float a, float b) {
    return (unsigned)f2bf(a) | ((unsigned)f2bf(b) << 16);
}

// sample-point offsets (pixel units), faithful to torch .view(2,n) reinterpret
__device__ const float c_ox[3][9] = {
    {-1.f, 0.f, 1.f, -1.f, 0.f, 1.f, -1.f, 0.f, 1.f},
    {-1.f, 2.4375f, -1.f, -2.4375f, 1.f, 2.4375f, 1.f, -2.4375f, 0.f},
    {-1.625f, -1.625f, -1.625f, 0.f, -1.625f, 1.625f, 0.f, -1.625f, 0.f}};
__device__ const float c_oy[3][9] = {
    {-1.f, -1.f, -1.f, 0.f, 0.f, 0.f, 1.f, 1.f, 1.f},
    {2.4375f, -1.f, -2.4375f, -1.f, 2.4375f, 1.f, -2.4375f, 1.f, 0.f},
    {0.f, 0.f, 1.625f, 1.625f, -1.625f, 1.625f, 0.f, 1.625f, 1.625f}};

// corner-branch tap tables (16 taps, single corner weight each)
__device__ const int tapX_cor[16] = {-1,-1, 2, 3,-1,-1,-3,-2, 1, 1, 2, 3, 1, 1,-3,-2};
__device__ const int tapY_cor[16] = { 2, 3,-1,-1,-3,-2,-1,-1, 2, 3, 1, 1,-3,-2, 1, 1};
__device__ const int tapR_cor[16] = { 4, 5, 2, 2, 0, 1, 2, 2, 4, 5, 3, 3, 0, 1, 3, 3};

// bilinear corner weight of fractional offset `off` at integer tap X
__device__ inline float cornw(float off, int X) {
    float f = floorf(off);
    float d = off - f;
    int fi = (int)f;
    return (X == fi) ? (1.f - d) : (X == fi + 1) ? d : 0.f;
}

// --------------------------- prep: fold BN + transpose ----------------------
__global__ __launch_bounds__(256) void prep_kernel(P53 ptrs, float* __restrict__ ws) {
    int i = blockIdx.x * 256 + threadIdx.x;
    const float* const* p = ptrs.p;
    // bf16 conv weights wA[tap][g(32)][M(192)][j(8)]
    if (i < 442368) {
        int tap = i / 49152, r = i % 49152;
        int g = r / 1536, r2 = r % 1536;
        int M = r2 >> 3, j = r2 & 7;
        int br = M >> 6, oc = M & 63, ic = g * 8 + j;
        float v = p[1 + 6 * br][(oc * 256 + ic) * 9 + tap] * p[3 + 6 * br][oc];
        ((ushortT*)(ws + OFF_CWT))[i] = f2bf(v);
        return;
    }
    i -= 442368;
    if (i < 192) {
        int br = i >> 6, oc = i & 63;
        ws[OFF_CB + i] = p[2 + 6 * br][oc] * p[3 + 6 * br][oc] + p[4 + 6 * br][oc];
        return;
    }
    i -= 192;
    if (i < 20736) {  // head conv weights [br][c64][k9][12] zero-padded
        int j = i % 12, k = (i / 12) % 9, c = (i / 108) % 64, br = i / 6912;
        int cnt = (br == 1) ? 12 : 3;
        const float* hw = (br == 0) ? p[5] : (br == 1) ? p[11] : p[17];
        ws[OFF_HWT + i] = (j < cnt) ? hw[(j * 64 + c) * 9 + k] : 0.f;
        return;
    }
    i -= 20736;
    if (i < 16384) {  // bf16 wQ[kk8][sub4][m64][j8]
        int j = i & 7, m = (i >> 3) & 63, sg = i >> 9;
        int k = (sg >> 2) * 32 + (sg & 3) * 8 + j;
        ((ushortT*)(ws + OFF_QWT))[i] = f2bf(p[19][m * 256 + k] * p[21][m]);
        return;
    }
    i -= 16384;
    if (i < 64) { ws[OFF_QB + i] = p[20][i] * p[21][i] + p[22][i]; return; }
    i -= 64;
    if (i < 483328) {  // W_eff bf16: units ctr[0,84) cor0[84,164) cor1[164,244) fg[244,472)
        int j = i & 7, m = (i >> 3) & 127, ug = i >> 10;
        int br, NG, NT, n, C, chb, ul;
        if (ug < 84)       { br = 0; NG = 9; NT = 9;  n = 9; C = 67; chb = 0;  ul = ug; }
        else if (ug < 164) { br = 1; NG = 5; NT = 16; n = 8; C = 76; chb = 0;  ul = ug - 84; }
        else if (ug < 244) { br = 1; NG = 5; NT = 16; n = 8; C = 76; chb = 40; ul = ug - 164; }
        else               { br = 2; NG = 9; NT = 25; n = 9; C = 67; chb = 0;  ul = ug - 244; }
        int t = ul / NG, g = ul % NG;
        int c = chb + g * 8 + j;
        float v = 0.f;
        if (t < NT && c < C) {
            int X, Y;
            if (br == 0)      { X = t % 3 - 1; Y = t / 3 - 1; }
            else if (br == 1) { X = tapX_cor[t]; Y = tapY_cor[t]; }
            else              { X = t % 5 - 2; Y = t / 5 - 2; }
            const float* wsrc = (m < 64) ? p[23 + 8 * br] : p[27 + 8 * br];
            int mo = (m < 64) ? m : m - 64;
            float sc = (m < 64) ? p[25 + 8 * br][mo] : p[29 + 8 * br][mo];
            int Cn = (C + 2) * n;
            float s = 0.f;
            for (int pp = 0; pp < n; ++pp) {
                float ww = cornw(c_ox[br][pp], X) * cornw(c_oy[br][pp], Y);
                if (ww != 0.f) s += ww * wsrc[mo * Cn + c * n + pp];
            }
            v = s * sc;
        }
        ((ushortT*)(ws + OFF_KVW))[i] = f2bf(v);
        return;
    }
    i -= 483328;
    if (i < 1152) {  // geo GA/GB/GC [br][which][128]
        int br = i / 384, rem = i % 384, which = rem >> 7, m = rem & 127;
        int n = (br == 1) ? 8 : 9, C = (br == 1) ? 76 : 67, Cn = (C + 2) * n;
        const float* wsrc = (m < 64) ? p[23 + 8 * br] : p[27 + 8 * br];
        int mo = (m < 64) ? m : m - 64;
        float sc = (m < 64) ? p[25 + 8 * br][mo] : p[29 + 8 * br][mo];
        float bb = (m < 64) ? p[24 + 8 * br][mo] : p[28 + 8 * br][mo];
        float tt = (m < 64) ? p[26 + 8 * br][mo] : p[30 + 8 * br][mo];
        float v = 0.f;
        if (which == 0) {
            for (int pp = 0; pp < n; ++pp) v += wsrc[mo * Cn + C * n + pp];
            v *= sc;
        } else if (which == 1) {
            for (int pp = 0; pp < n; ++pp) v += wsrc[mo * Cn + (C + 1) * n + pp];
            v *= sc;
        } else {
            for (int pp = 0; pp < n; ++pp)
                v += wsrc[mo * Cn + C * n + pp] * c_ox[br][pp]
                   + wsrc[mo * Cn + (C + 1) * n + pp] * c_oy[br][pp];
            v = v * sc * 0.0078125f + bb * sc + tt;
        }
        ws[OFF_GEO + br * 384 + which * 128 + m] = v;
        return;
    }
    i -= 1152;
    if (i < 81920) {  // bf16 wP1[kk10][sub4][M256][j8], K=320 extended
        int j = i & 7, M = (i >> 3) & 255, sg = i >> 11;
        int k = (sg >> 2) * 32 + (sg & 3) * 8 + j;
        int nh = M >> 6, oc = M & 63;
        float sc = p[49][nh * 64 + oc];
        float v;
        if (k < 256) v = p[47][(nh * 64 + oc) * 272 + k] * sc;
        else {
            int k2 = k - 256, nh2 = k2 >> 4, va = k2 & 15;
            v = (nh2 == nh) ? p[47][(nh * 64 + oc) * 272 + 256 + va] * sc : 0.f;
        }
        ((ushortT*)(ws + OFF_P1WT))[i] = f2bf(v);
        return;
    }
    i -= 81920;
    if (i < 256) { ws[OFF_P1B + i] = p[48][i] * p[49][i] + p[50][i]; return; }
}

// ------------- conv3x3 base(256) -> 192 feats via bf16 MFMA -----------------
__global__ __launch_bounds__(256) void conv_base_mfma(
    const float* __restrict__ base, const ushortT* __restrict__ wA,
    const float* __restrict__ cb, float* __restrict__ feats)
{
    const int wv = threadIdx.x >> 6, lane = threadIdx.x & 63;
    const int sub = lane >> 4, ln = lane & 15;
    const int xh = blockIdx.x, h = blockIdx.y, b = blockIdx.z;
    __shared__ __align__(16) ushortT sbuf[8 * 3 * 66 * 8];

    floatx4 acc[3][4];
    #pragma unroll
    for (int mt = 0; mt < 3; ++mt)
        #pragma unroll
        for (int nt = 0; nt < 4; ++nt)
            #pragma unroll
            for (int r = 0; r < 4; ++r) acc[mt][nt][r] = 0.f;

    const float* inb = base + (size_t)b * 256 * HW;
    const int icp = threadIdx.x & 3;

    for (int s = 0; s < 4; ++s) {
        const int icbase = s * 64;
        __syncthreads();
        for (int it = 0; it < 25; ++it) {
            int idx = threadIdx.x + it * 256;
            if (idx < 6336) {
                int elem = idx >> 2;
                int c = elem % 66, t2 = elem / 66;
                int r = t2 % 3, icg = t2 / 3;
                int gh = h + r - 1, gw = xh * 64 + c - 1;
                float v0 = 0.f, v1 = 0.f;
                if ((unsigned)gh < 128u && (unsigned)gw < 128u) {
                    const float* pp = inb + (size_t)(icbase + icg * 8 + icp * 2) * HW + gh * WIMG + gw;
                    v0 = pp[0]; v1 = pp[HW];
                }
                ((unsigned*)sbuf)[idx] = packbf(v0, v1);
            }
        }
        __syncthreads();
        #pragma unroll
        for (int tap = 0; tap < 9; ++tap) {
            const int ky = tap / 3, kx = tap % 3;
            #pragma unroll
            for (int icc = 0; icc < 2; ++icc) {
                const int icgl = icc * 4 + sub;
                short8 Bf[4];
                #pragma unroll
                for (int nt = 0; nt < 4; ++nt) {
                    int c = nt * 16 + ln + kx;
                    Bf[nt] = *(const short8*)(sbuf + ((icgl * 3 + ky) * 66 + c) * 8);
                }
                const int g = s * 8 + icc * 4 + sub;
                short8 Af[3];
                #pragma unroll
                for (int mt = 0; mt < 3; ++mt) {
                    int m = wv * 48 + mt * 16 + ln;
                    Af[mt] = *(const short8*)(wA + (((size_t)tap * 32 + g) * 192 + m) * 8);
                }
                #pragma unroll
                for (int mt = 0; mt < 3; ++mt)
                    #pragma unroll
                    for (int nt = 0; nt < 4; ++nt)
                        acc[mt][nt] = __builtin_amdgcn_mfma_f32_16x16x32_bf16(
                            Af[mt], Bf[nt], acc[mt][nt], 0, 0, 0);
            }
        }
    }
    #pragma unroll
    for (int mt = 0; mt < 3; ++mt)
        #pragma unroll
        for (int nt = 0; nt < 4; ++nt)
            #pragma unroll
            for (int r = 0; r < 4; ++r) {
                int Mi = wv * 48 + mt * 16 + sub * 4 + r;
                int px = xh * 64 + nt * 16 + ln;
                float v = acc[mt][nt][r] + cb[Mi];
                feats[((size_t)b * 192 + Mi) * HW + h * WIMG + px] = fmaxf(v, 0.f);
            }
}

// ---------------- head 3x3 convs (64 -> 3/12/3) -> d_out ch 0..17 -----------
__global__ __launch_bounds__(256) void conv_head_kernel(
    const float* __restrict__ feats, const float* __restrict__ hwt_all,
    const float* __restrict__ chb, const float* __restrict__ ohb,
    const float* __restrict__ fhb, float* __restrict__ out)
{
    const int tx = threadIdx.x & 15, ty = threadIdx.x >> 4;
    const int w0 = blockIdx.x << 4, h0 = blockIdx.y << 4;
    const int br = blockIdx.z % 3, b = blockIdx.z / 3;
    const int cnt = (br == 1) ? 12 : 3;
    const int mapb = (br == 0) ? 0 : (br == 1) ? 3 : 15;
    const float* bias = (br == 0) ? chb : (br == 1) ? ohb : fhb;
    const float* hwt = hwt_all + br * 6912;
    __shared__ float tile[4][18][18];
    float acc[12];
    #pragma unroll
    for (int j = 0; j < 12; ++j) acc[j] = (j < cnt) ? bias[j] : 0.f;
    const float* fb = feats + ((size_t)b * 192 + br * 64) * HW;
    for (int c0 = 0; c0 < 64; c0 += 4) {
        __syncthreads();
        for (int i = threadIdx.x; i < 1296; i += 256) {
            int cc = i / 324, r = (i % 324) / 18, col = i % 18;
            int gh = h0 + r - 1, gw = w0 + col - 1;
            float v = 0.f;
            if ((unsigned)gh < 128u && (unsigned)gw < 128u)
                v = fb[(c0 + cc) * HW + gh * WIMG + gw];
            tile[cc][r][col] = v;
        }
        __syncthreads();
        #pragma unroll
        for (int cc = 0; cc < 4; ++cc) {
            float in[9];
            #pragma unroll
            for (int ky = 0; ky < 3; ++ky)
                #pragma unroll
                for (int kx = 0; kx < 3; ++kx)
                    in[ky * 3 + kx] = tile[cc][ty + ky][tx + kx];
            const float* wr = hwt + (c0 + cc) * 108;
            #pragma unroll
            for (int k = 0; k < 9; ++k)
                #pragma unroll
                for (int j = 0; j < 12; ++j)
                    acc[j] = fmaf(wr[k * 12 + j], in[k], acc[j]);
        }
    }
    float* ob = out + ((size_t)b * 26 + mapb) * HW + (h0 + ty) * WIMG + (w0 + tx);
    #pragma unroll
    for (int j = 0; j < 12; ++j)
        if (j < cnt) ob[j * HW] = acc[j];
}

// ----------------------------- q via bf16 MFMA ------------------------------
__global__ __launch_bounds__(256) void q_mfma(const float* __restrict__ base,
                                              float* __restrict__ ws)
{
    const int wv = threadIdx.x >> 6, lane = threadIdx.x & 63;
    const int sub = lane >> 4, ln = lane & 15;
    const int px0 = blockIdx.x * 64, b = blockIdx.y;
    const ushortT* wQ = (const ushortT*)(ws + OFF_QWT);
    const float* qb = ws + OFF_QB;
    __shared__ __align__(16) ushortT xb[32 * 64 * 8];

    const int mypx = threadIdx.x & 63, q4 = threadIdx.x >> 6;
    const float* inb = base + (size_t)b * 256 * HW + px0 + mypx;
    #pragma unroll
    for (int icp = 0; icp < 32; ++icp) {
        int ic = q4 * 64 + icp * 2;
        float v0 = inb[(size_t)ic * HW], v1 = inb[(size_t)(ic + 1) * HW];
        int g = ic >> 3, wo = (ic & 7) >> 1;
        ((unsigned*)xb)[(g * 64 + mypx) * 4 + wo] = packbf(v0, v1);
    }
    __syncthreads();

    floatx4 acc[4];
    #pragma unroll
    for (int mt = 0; mt < 4; ++mt)
        #pragma unroll
        for (int r = 0; r < 4; ++r) acc[mt][r] = 0.f;
    #pragma unroll
    for (int kk = 0; kk < 8; ++kk) {
        short8 Bf = *(const short8*)(xb + (((kk * 4 + sub) * 64) + wv * 16 + ln) * 8);
        #pragma unroll
        for (int mt = 0; mt < 4; ++mt) {
            short8 Af = *(const short8*)(wQ + (((kk * 4 + sub) * 64) + mt * 16 + ln) * 8);
            acc[mt] = __builtin_amdgcn_mfma_f32_16x16x32_bf16(Af, Bf, acc[mt], 0, 0, 0);
        }
    }
    float* q = ws + OFF_Q + (size_t)b * 64 * HW;
    #pragma unroll
    for (int mt = 0; mt < 4; ++mt)
        #pragma unroll
        for (int r = 0; r < 4; ++r) {
            int Mi = mt * 16 + sub * 4 + r;
            q[(size_t)Mi * HW + px0 + wv * 16 + ln] = fmaxf(acc[mt][r] + qb[Mi], 0.f);
        }
}

// ------------- kv as sparse-tap conv via bf16 MFMA --------------------------
// M=128 (k 0..63, v 64..127), N=64 px, K = NTAP x padded-channels (8-groups).
// LDS stages the raw window once; taps index it by (row,col) offset.
template<int BR, int NGRP, int NTAP, int ROWS, int COLS, int XMIN, int NCHUNK,
         int NPH, int MAPCH, int MAPB>
__global__ __launch_bounds__(256) void kv_conv(
    const float* __restrict__ feats_all, const float* __restrict__ outmaps,
    const ushortT* __restrict__ wU0, const float* __restrict__ geo,
    float* __restrict__ kvout)
{
    const int wv = threadIdx.x >> 6, lane = threadIdx.x & 63;
    const int sub = lane >> 4, ln = lane & 15;
    const int x0 = blockIdx.x * 64, h = blockIdx.y, b = blockIdx.z;
    __shared__ __align__(16) ushortT sbuf[NGRP * ROWS * COLS * 8];

    floatx4 acc[2][4];
    #pragma unroll
    for (int mt = 0; mt < 2; ++mt)
        #pragma unroll
        for (int nt = 0; nt < 4; ++nt)
            #pragma unroll
            for (int r = 0; r < 4; ++r) acc[mt][nt][r] = 0.f;

    const float* fbase = feats_all + ((size_t)b * 192 + BR * 64) * HW;
    const float* mbase = outmaps + ((size_t)b * 26 + MAPB) * HW;

    #pragma unroll
    for (int ph = 0; ph < NPH; ++ph) {
        const int chb = ph * NGRP * 8;
        const ushortT* wU = wU0 + (size_t)ph * (NCHUNK * 4 * 1024);
        __syncthreads();
        constexpr int WWORDS = NGRP * ROWS * COLS * 4;
        for (int it = 0; it < (WWORDS + 255) / 256; ++it) {
            int idx = threadIdx.x + it * 256;
            if (idx < WWORDS) {
                int elem = idx >> 2, wo = idx & 3;
                int grp = elem / (ROWS * COLS);
                int rem = elem % (ROWS * COLS);
                int r = rem / COLS, col = rem % COLS;
                int dy = (ROWS == 6) ? ((r < 3) ? r - 3 : r - 2) : (r - ROWS / 2);
                int gh = h + dy, gw = x0 + col + XMIN;
                float v0 = 0.f, v1 = 0.f;
                if ((unsigned)gh < 128u && (unsigned)gw < 128u) {
                    int c0 = chb + grp * 8 + wo * 2;
                    int off = gh * WIMG + gw;
                    v0 = (c0 < 64) ? fbase[(size_t)c0 * HW + off]
                       : (c0 < 64 + MAPCH) ? mbase[(size_t)(c0 - 64) * HW + off] : 0.f;
                    int c1 = c0 + 1;
                    v1 = (c1 < 64) ? fbase[(size_t)c1 * HW + off]
                       : (c1 < 64 + MAPCH) ? mbase[(size_t)(c1 - 64) * HW + off] : 0.f;
                }
                ((unsigned*)sbuf)[idx] = packbf(v0, v1);
            }
        }
        __syncthreads();
        #pragma unroll
        for (int k = 0; k < NCHUNK; ++k) {
            int u = k * 4 + sub;
            int t = u / NGRP, g = u - t * NGRP;
            if (t >= NTAP) t = 0;  // padded units: A weights are zero
            int dxv, ry;
            if (BR == 0)      { dxv = t % 3 - 1; ry = t / 3; }
            else if (BR == 1) { dxv = tapX_cor[t]; ry = tapR_cor[t]; }
            else              { dxv = t % 5 - 2; ry = t / 5; }
            int bbase = (g * ROWS + ry) * COLS + (dxv - XMIN);
            short8 Bf[4];
            #pragma unroll
            for (int nt = 0; nt < 4; ++nt)
                Bf[nt] = *(const short8*)(sbuf + (bbase + nt * 16 + ln) * 8);
            short8 Af[2];
            #pragma unroll
            for (int mt = 0; mt < 2; ++mt)
                Af[mt] = *(const short8*)(wU + ((size_t)u * 128 + wv * 32 + mt * 16 + ln) * 8);
            #pragma unroll
            for (int mt = 0; mt < 2; ++mt)
                #pragma unroll
                for (int nt = 0; nt < 4; ++nt)
                    acc[mt][nt] = __builtin_amdgcn_mfma_f32_16x16x32_bf16(
                        Af[mt], Bf[nt], acc[mt][nt], 0, 0, 0);
        }
    }
    // epilogue: + GA*fx + GB*fy + GC (bias folded), relu
    const float fy = (h + 0.5f) * 0.0078125f;
    #pragma unroll
    for (int mt = 0; mt < 2; ++mt)
        #pragma unroll
        for (int nt = 0; nt < 4; ++nt) {
            int px = x0 + nt * 16 + ln;
            float fx = (px + 0.5f) * 0.0078125f;
            #pragma unroll
            for (int r = 0; r < 4; ++r) {
                int Mi = wv * 32 + mt * 16 + sub * 4 + r;
                float v = acc[mt][nt][r] + geo[Mi] * fx + geo[128 + Mi] * fy + geo[256 + Mi];
                kvout[((size_t)(BR * 4 + b) * 128 + Mi) * HW + h * WIMG + px] = fmaxf(v, 0.f);
            }
        }
}

// ---------- attention softmax + p1(MFMA, K=320) + relu + p2 -> out ----------
__global__ __launch_bounds__(256) void attn_pred_mfma(
    const float* __restrict__ base, float* __restrict__ ws,
    const float* __restrict__ p2w, const float* __restrict__ p2b,
    float* __restrict__ out)
{
    const int wv = threadIdx.x >> 6, lane = threadIdx.x & 63;
    const int sub = lane >> 4, ln = lane & 15;
    const int px0 = blockIdx.x * 64, b = blockIdx.y;
    const ushortT* wP1 = (const ushortT*)(ws + OFF_P1WT);
    const float* p1b = ws + OFF_P1B;
    __shared__ __align__(16) ushortT xbuf[40 * 64 * 8];

    const int mypx = threadIdx.x & 63, nh = threadIdx.x >> 6;
    const int gpx = px0 + mypx;
    const float* inb = base + (size_t)b * 256 * HW + gpx;
    #pragma unroll
    for (int icp = 0; icp < 32; ++icp) {
        int ic = nh * 64 + icp * 2;
        float v0 = inb[(size_t)ic * HW], v1 = inb[(size_t)(ic + 1) * HW];
        int g = ic >> 3, wo = (ic & 7) >> 1;
        ((unsigned*)xbuf)[(g * 64 + mypx) * 4 + wo] = packbf(v0, v1);
    }
    {
        const float* q  = ws + OFF_Q + ((size_t)b * 64 + nh * 16) * HW + gpx;
        const float* kv = ws + OFF_KV;
        float l[3];
        #pragma unroll
        for (int br = 0; br < 3; ++br) {
            float s = 0.f;
            #pragma unroll
            for (int ko = 0; ko < 16; ++ko)
                s = fmaf(q[(size_t)ko * HW],
                         kv[(size_t)((br * 4 + b) * 128 + nh * 16 + ko) * HW + gpx], s);
            l[br] = s;
        }
        float m = fmaxf(l[0], fmaxf(l[1], l[2]));
        float e0 = __expf(l[0] - m), e1 = __expf(l[1] - m), e2 = __expf(l[2] - m);
        float inv = 1.f / (e0 + e1 + e2);
        float aw0 = e0 * inv, aw1 = e1 * inv, aw2 = e2 * inv;
        #pragma unroll
        for (int vap = 0; vap < 8; ++vap) {
            int va0 = vap * 2, va1 = vap * 2 + 1;
            float a0 =
                aw0 * kv[(size_t)((0 * 4 + b) * 128 + 64 + nh * 16 + va0) * HW + gpx] +
                aw1 * kv[(size_t)((1 * 4 + b) * 128 + 64 + nh * 16 + va0) * HW + gpx] +
                aw2 * kv[(size_t)((2 * 4 + b) * 128 + 64 + nh * 16 + va0) * HW + gpx];
            float a1 =
                aw0 * kv[(size_t)((0 * 4 + b) * 128 + 64 + nh * 16 + va1) * HW + gpx] +
                aw1 * kv[(size_t)((1 * 4 + b) * 128 + 64 + nh * 16 + va1) * HW + gpx] +
                aw2 * kv[(size_t)((2 * 4 + b) * 128 + 64 + nh * 16 + va1) * HW + gpx];
            int g = 32 + nh * 2 + (vap >> 2), wo = vap & 3;
            ((unsigned*)xbuf)[(g * 64 + mypx) * 4 + wo] = packbf(a0, a1);
        }
    }
    __syncthreads();

    floatx4 acc[4][4];
    #pragma unroll
    for (int mt = 0; mt < 4; ++mt)
        #pragma unroll
        for (int nt = 0; nt < 4; ++nt)
            #pragma unroll
            for (int r = 0; r < 4; ++r) acc[mt][nt][r] = 0.f;
    #pragma unroll
    for (int kk = 0; kk < 10; ++kk) {
        short8 Bf[4];
        #pragma unroll
        for (int nt = 0; nt < 4; ++nt)
            Bf[nt] = *(const short8*)(xbuf + (((kk * 4 + sub) * 64) + nt * 16 + ln) * 8);
        #pragma unroll
        for (int mt = 0; mt < 4; ++mt) {
            short8 Af = *(const short8*)(wP1 + (((size_t)(kk * 4 + sub) * 256) + wv * 64 + mt * 16 + ln) * 8);
            #pragma unroll
            for (int nt = 0; nt < 4; ++nt)
                acc[mt][nt] = __builtin_amdgcn_mfma_f32_16x16x32_bf16(Af, Bf[nt], acc[mt][nt], 0, 0, 0);
        }
    }

    float po0[4] = {0.f, 0.f, 0.f, 0.f}, po1[4] = {0.f, 0.f, 0.f, 0.f};
    #pragma unroll
    for (int mt = 0; mt < 4; ++mt)
        #pragma unroll
        for (int r = 0; r < 4; ++r) {
            int oc = mt * 16 + sub * 4 + r;
            float bias = p1b[wv * 64 + oc];
            float w0 = p2w[(wv * 2 + 0) * 64 + oc];
            float w1 = p2w[(wv * 2 + 1) * 64 + oc];
            #pragma unroll
            for (int nt = 0; nt < 4; ++nt) {
                float hv = fmaxf(acc[mt][nt][r] + bias, 0.f);
                po0[nt] = fmaf(w0, hv, po0[nt]);
                po1[nt] = fmaf(w1, hv, po1[nt]);
            }
        }
    #pragma unroll
    for (int nt = 0; nt < 4; ++nt) {
        po0[nt] += __shfl_xor(po0[nt], 16);
        po0[nt] += __shfl_xor(po0[nt], 32);
        po1[nt] += __shfl_xor(po1[nt], 16);
        po1[nt] += __shfl_xor(po1[nt], 32);
    }
    if (sub == 0) {
        #pragma unroll
        for (int nt = 0; nt < 4; ++nt) {
            int px = px0 + nt * 16 + ln;
            out[((size_t)b * 26 + 18 + wv * 2 + 0) * HW + px] = po0[nt] + p2b[wv * 2 + 0];
            out[((size_t)b * 26 + 18 + wv * 2 + 1) * HW + px] = po1[nt] + p2b[wv * 2 + 1];
        }
    }
}

// ---------------------------------------------------------------------------
extern "C" void kernel_launch(void* const* d_in, const int* in_sizes, int n_in,
                              void* d_out, int out_size, void* d_ws, size_t ws_size,
                              hipStream_t stream) {
    (void)in_sizes; (void)n_in; (void)out_size; (void)ws_size;
    float* ws  = (float*)d_ws;
    float* out = (float*)d_out;
    const float* base = (const float*)d_in[0];
    P53 ptrs;
    for (int i = 0; i < 53; ++i) ptrs.p[i] = (const float*)d_in[i];

    prep_kernel<<<4088, 256, 0, stream>>>(ptrs, ws);
    conv_base_mfma<<<dim3(2, 128, 4), 256, 0, stream>>>(
        base, (const ushortT*)(ws + OFF_CWT), ws + OFF_CB, ws + OFF_FEATS);
    conv_head_kernel<<<dim3(8, 8, 12), 256, 0, stream>>>(ws + OFF_FEATS, ws + OFF_HWT,
                                                         (const float*)d_in[6],
                                                         (const float*)d_in[12],
                                                         (const float*)d_in[18], out);
    q_mfma<<<dim3(256, 4), 256, 0, stream>>>(base, ws);

    const ushortT* kvw = (const ushortT*)(ws + OFF_KVW);
    // ctr: 9 taps, 9 grp (72ch), rows {-1,0,1}, cols 66, units 81 -> 21 chunks
    kv_conv<0, 9, 9, 3, 66, -1, 21, 1, 3, 0><<<dim3(2, 128, 4), 256, 0, stream>>>(
        ws + OFF_FEATS, out, kvw, ws + OFF_GEO, ws + OFF_KV);
    // cor: 16 taps, 2 phases x 5 grp (40ch), rows {-3..-1,1..3}, cols 70, 20 chunks/ph
    kv_conv<1, 5, 16, 6, 70, -3, 20, 2, 12, 3><<<dim3(2, 128, 4), 256, 0, stream>>>(
        ws + OFF_FEATS, out, kvw + 86016, ws + OFF_GEO + 384, ws + OFF_KV);
    // fg: 25 taps, 9 grp (72ch), rows {-2..2}, cols 68, units 225 -> 57 chunks
    kv_conv<2, 9, 25, 5, 68, -2, 57, 1, 3, 15><<<dim3(2, 128, 4), 256, 0, stream>>>(
        ws + OFF_FEATS, out, kvw + 249856, ws + OFF_GEO + 768, ws + OFF_KV);

    attn_pred_mfma<<<dim3(256, 4), 256, 0, stream>>>(base, ws, (const float*)d_in[51],
                                                     (const float*)d_in[52], out);
}

// Round 5
// 567.649 us; speedup vs baseline: 5.2164x; 1.2477x over previous
//
#include <hip/hip_runtime.h>
#include <hip/hip_bf16.h>
#include <math.h>

// ---------------------------------------------------------------------------
// HydraFusionHead: B=4, IN_CH=256, HEAD_CH=64, H=W=128, NH=4, KEY=VAL=16
// All GEMM-shaped work on bf16 MFMA. Inputs pre-converted once per launch to
// padded 8ch-interleaved bf16 (pass A: base, pad 1; pass B: feats+maps,
// pad 3) so every kernel's LDS staging is 1 load + 1 ds_write_b128 per 16B.
// KV activations stored bf16. BN folded by prep.
// ---------------------------------------------------------------------------

#define HW 16384
#define WIMG 128

typedef unsigned short ushortT;
typedef __attribute__((ext_vector_type(8))) short short8;
typedef __attribute__((ext_vector_type(4))) float floatx4;

// ws layout (float offsets)
constexpr size_t OFF_FEATS = 0;                    // fp32 [4][192][HW]
constexpr size_t OFF_Q     = 12582912;             // fp32 [4][64][HW]
constexpr size_t OFF_KV    = 16777216;             // bf16 [3][4][128][HW] (25.2M us)
constexpr size_t OFF_A16   = 29360128;             // bf16 [4][32][130][130][8]
constexpr size_t OFF_B16   = 38012928;             // bf16 [4][28][134][134][8]
constexpr size_t OFF_CWT   = 46057216;             // bf16 wA [9][32][192][8]
constexpr size_t OFF_CB    = OFF_CWT + 442368;     // [3][64] fp32
constexpr size_t OFF_HWT   = OFF_CB + 192;         // [3][64][9][12] fp32 zero-padded
constexpr size_t OFF_QWT   = OFF_HWT + 20736;      // bf16 wQ
constexpr size_t OFF_QB    = OFF_QWT + 16384;      // [64]
constexpr size_t OFF_KVW   = OFF_QB + 64;          // bf16 W_eff [472][128][8]
constexpr size_t OFF_GEO   = OFF_KVW + 241664;     // fp32 [3][3][128]
constexpr size_t OFF_P1WT  = OFF_GEO + 1152;       // bf16 wP1
constexpr size_t OFF_P1B   = OFF_P1WT + 81920;     // [256]

struct P53 { const float* p[53]; };

__device__ inline ushortT f2bf(float f) {
    unsigned u = __float_as_uint(f);
    unsigned r = (u + 0x7FFFu + ((u >> 16) & 1u)) >> 16;
    return (ushortT)r;
}
__device__ inline unsigned packbf(float a, float b) {
    return (unsigned)f2bf(a) | ((unsigned)f2bf(b) << 16);
}
__device__ inline float bf2f(ushortT u) {
    return __uint_as_float((unsigned)u << 16);
}

// sample-point offsets (pixel units), faithful to torch .view(2,n) reinterpret
__device__ const float c_ox[3][9] = {
    {-1.f, 0.f, 1.f, -1.f, 0.f, 1.f, -1.f, 0.f, 1.f},
    {-1.f, 2.4375f, -1.f, -2.4375f, 1.f, 2.4375f, 1.f, -2.4375f, 0.f},
    {-1.625f, -1.625f, -1.625f, 0.f, -1.625f, 1.625f, 0.f, -1.625f, 0.f}};
__device__ const float c_oy[3][9] = {
    {-1.f, -1.f, -1.f, 0.f, 0.f, 0.f, 1.f, 1.f, 1.f},
    {2.4375f, -1.f, -2.4375f, -1.f, 2.4375f, 1.f, -2.4375f, 1.f, 0.f},
    {0.f, 0.f, 1.625f, 1.625f, -1.625f, 1.625f, 0.f, 1.625f, 1.625f}};

// corner-branch tap tables (16 taps)
__device__ const int tapX_cor[16] = {-1,-1, 2, 3,-1,-1,-3,-2, 1, 1, 2, 3, 1, 1,-3,-2};
__device__ const int tapY_cor[16] = { 2, 3,-1,-1,-3,-2,-1,-1, 2, 3, 1, 1,-3,-2, 1, 1};
__device__ const int tapR_cor[16] = { 4, 5, 2, 2, 0, 1, 2, 2, 4, 5, 3, 3, 0, 1, 3, 3};

__device__ inline float cornw(float off, int X) {
    float f = floorf(off);
    float d = off - f;
    int fi = (int)f;
    return (X == fi) ? (1.f - d) : (X == fi + 1) ? d : 0.f;
}

// --------------------------- prep: fold BN + transpose ----------------------
__global__ __launch_bounds__(256) void prep_kernel(P53 ptrs, float* __restrict__ ws) {
    int i = blockIdx.x * 256 + threadIdx.x;
    const float* const* p = ptrs.p;
    if (i < 442368) {  // bf16 conv weights wA[tap][g32][M192][j8]
        int tap = i / 49152, r = i % 49152;
        int g = r / 1536, r2 = r % 1536;
        int M = r2 >> 3, j = r2 & 7;
        int br = M >> 6, oc = M & 63, ic = g * 8 + j;
        float v = p[1 + 6 * br][(oc * 256 + ic) * 9 + tap] * p[3 + 6 * br][oc];
        ((ushortT*)(ws + OFF_CWT))[i] = f2bf(v);
        return;
    }
    i -= 442368;
    if (i < 192) {
        int br = i >> 6, oc = i & 63;
        ws[OFF_CB + i] = p[2 + 6 * br][oc] * p[3 + 6 * br][oc] + p[4 + 6 * br][oc];
        return;
    }
    i -= 192;
    if (i < 20736) {  // head conv weights [br][c64][k9][12] zero-padded
        int j = i % 12, k = (i / 12) % 9, c = (i / 108) % 64, br = i / 6912;
        int cnt = (br == 1) ? 12 : 3;
        const float* hw = (br == 0) ? p[5] : (br == 1) ? p[11] : p[17];
        ws[OFF_HWT + i] = (j < cnt) ? hw[(j * 64 + c) * 9 + k] : 0.f;
        return;
    }
    i -= 20736;
    if (i < 16384) {  // bf16 wQ[kk8][sub4][m64][j8]
        int j = i & 7, m = (i >> 3) & 63, sg = i >> 9;
        int k = (sg >> 2) * 32 + (sg & 3) * 8 + j;
        ((ushortT*)(ws + OFF_QWT))[i] = f2bf(p[19][m * 256 + k] * p[21][m]);
        return;
    }
    i -= 16384;
    if (i < 64) { ws[OFF_QB + i] = p[20][i] * p[21][i] + p[22][i]; return; }
    i -= 64;
    if (i < 483328) {  // W_eff bf16: units ctr[0,84) cor0[84,164) cor1[164,244) fg[244,472)
        int j = i & 7, m = (i >> 3) & 127, ug = i >> 10;
        int br, NG, NT, n, C, chb, ul;
        if (ug < 84)       { br = 0; NG = 9; NT = 9;  n = 9; C = 67; chb = 0;  ul = ug; }
        else if (ug < 164) { br = 1; NG = 5; NT = 16; n = 8; C = 76; chb = 0;  ul = ug - 84; }
        else if (ug < 244) { br = 1; NG = 5; NT = 16; n = 8; C = 76; chb = 40; ul = ug - 164; }
        else               { br = 2; NG = 9; NT = 25; n = 9; C = 67; chb = 0;  ul = ug - 244; }
        int t = ul / NG, g = ul % NG;
        int c = chb + g * 8 + j;
        float v = 0.f;
        if (t < NT && c < C) {
            int X, Y;
            if (br == 0)      { X = t % 3 - 1; Y = t / 3 - 1; }
            else if (br == 1) { X = tapX_cor[t]; Y = tapY_cor[t]; }
            else              { X = t % 5 - 2; Y = t / 5 - 2; }
            const float* wsrc = (m < 64) ? p[23 + 8 * br] : p[27 + 8 * br];
            int mo = (m < 64) ? m : m - 64;
            float sc = (m < 64) ? p[25 + 8 * br][mo] : p[29 + 8 * br][mo];
            int Cn = (C + 2) * n;
            float s = 0.f;
            for (int pp = 0; pp < n; ++pp) {
                float ww = cornw(c_ox[br][pp], X) * cornw(c_oy[br][pp], Y);
                if (ww != 0.f) s += ww * wsrc[mo * Cn + c * n + pp];
            }
            v = s * sc;
        }
        ((ushortT*)(ws + OFF_KVW))[i] = f2bf(v);
        return;
    }
    i -= 483328;
    if (i < 1152) {  // geo GA/GB/GC [br][which][128]
        int br = i / 384, rem = i % 384, which = rem >> 7, m = rem & 127;
        int n = (br == 1) ? 8 : 9, C = (br == 1) ? 76 : 67, Cn = (C + 2) * n;
        const float* wsrc = (m < 64) ? p[23 + 8 * br] : p[27 + 8 * br];
        int mo = (m < 64) ? m : m - 64;
        float sc = (m < 64) ? p[25 + 8 * br][mo] : p[29 + 8 * br][mo];
        float bb = (m < 64) ? p[24 + 8 * br][mo] : p[28 + 8 * br][mo];
        float tt = (m < 64) ? p[26 + 8 * br][mo] : p[30 + 8 * br][mo];
        float v = 0.f;
        if (which == 0) {
            for (int pp = 0; pp < n; ++pp) v += wsrc[mo * Cn + C * n + pp];
            v *= sc;
        } else if (which == 1) {
            for (int pp = 0; pp < n; ++pp) v += wsrc[mo * Cn + (C + 1) * n + pp];
            v *= sc;
        } else {
            for (int pp = 0; pp < n; ++pp)
                v += wsrc[mo * Cn + C * n + pp] * c_ox[br][pp]
                   + wsrc[mo * Cn + (C + 1) * n + pp] * c_oy[br][pp];
            v = v * sc * 0.0078125f + bb * sc + tt;
        }
        ws[OFF_GEO + br * 384 + which * 128 + m] = v;
        return;
    }
    i -= 1152;
    if (i < 81920) {  // bf16 wP1[kk10][sub4][M256][j8], K=320 extended
        int j = i & 7, M = (i >> 3) & 255, sg = i >> 11;
        int k = (sg >> 2) * 32 + (sg & 3) * 8 + j;
        int nh = M >> 6, oc = M & 63;
        float sc = p[49][nh * 64 + oc];
        float v;
        if (k < 256) v = p[47][(nh * 64 + oc) * 272 + k] * sc;
        else {
            int k2 = k - 256, nh2 = k2 >> 4, va = k2 & 15;
            v = (nh2 == nh) ? p[47][(nh * 64 + oc) * 272 + 256 + va] * sc : 0.f;
        }
        ((ushortT*)(ws + OFF_P1WT))[i] = f2bf(v);
        return;
    }
    i -= 81920;
    if (i < 256) { ws[OFF_P1B + i] = p[48][i] * p[49][i] + p[50][i]; return; }
}

// ---------- pass A: base fp32 -> padded interleaved bf16 (pad 1) ------------
__global__ __launch_bounds__(256) void pass_a(const float* __restrict__ base,
                                              ushortT* __restrict__ dst) {
    int idx = blockIdx.x * 256 + threadIdx.x;
    if (idx >= 4 * 32 * 130 * 130) return;
    int col = idx % 130, t = idx / 130;
    int row = t % 130; t /= 130;
    int icg = t & 31, b = t >> 5;
    int h = row - 1, w = col - 1;
    unsigned wds[4] = {0u, 0u, 0u, 0u};
    if ((unsigned)h < 128u && (unsigned)w < 128u) {
        const float* s = base + (size_t)(b * 256 + icg * 8) * HW + h * WIMG + w;
        #pragma unroll
        for (int jp = 0; jp < 4; ++jp)
            wds[jp] = packbf(s[(size_t)(2 * jp) * HW], s[(size_t)(2 * jp + 1) * HW]);
    }
    unsigned* d = (unsigned*)(dst + (size_t)idx * 8);
    d[0] = wds[0]; d[1] = wds[1]; d[2] = wds[2]; d[3] = wds[3];
}

// ---- pass B: feats+maps -> padded interleaved bf16 (pad 3), 28 groups ------
__global__ __launch_bounds__(256) void pass_b(const float* __restrict__ feats,
                                              const float* __restrict__ out,
                                              ushortT* __restrict__ dst) {
    int idx = blockIdx.x * 256 + threadIdx.x;
    if (idx >= 4 * 28 * 134 * 134) return;
    int col = idx % 134, t = idx / 134;
    int row = t % 134; t /= 134;
    int u = t % 28, b = t / 28;
    int br = (u < 9) ? 0 : (u < 19) ? 1 : 2;
    int g = u - ((br == 0) ? 0 : (br == 1) ? 9 : 19);
    int C = (br == 1) ? 76 : 67;
    int mapb = (br == 0) ? 0 : (br == 1) ? 3 : 15;
    int h = row - 3, w = col - 3;
    unsigned wds[4] = {0u, 0u, 0u, 0u};
    if ((unsigned)h < 128u && (unsigned)w < 128u) {
        int off = h * WIMG + w;
        float v[8];
        #pragma unroll
        for (int j = 0; j < 8; ++j) {
            int c = g * 8 + j;
            float x = 0.f;
            if (c < 64) x = feats[(size_t)(b * 192 + br * 64 + c) * HW + off];
            else if (c < C) x = out[(size_t)(b * 26 + mapb + c - 64) * HW + off];
            v[j] = x;
        }
        #pragma unroll
        for (int jp = 0; jp < 4; ++jp) wds[jp] = packbf(v[2 * jp], v[2 * jp + 1]);
    }
    unsigned* d = (unsigned*)(dst + (size_t)idx * 8);
    d[0] = wds[0]; d[1] = wds[1]; d[2] = wds[2]; d[3] = wds[3];
}

// ------------- conv3x3 base(256) -> 192 feats via bf16 MFMA -----------------
__global__ __launch_bounds__(256) void conv_base_mfma(
    const ushortT* __restrict__ a16, const ushortT* __restrict__ wA,
    const float* __restrict__ cb, float* __restrict__ feats)
{
    const int wv = threadIdx.x >> 6, lane = threadIdx.x & 63;
    const int sub = lane >> 4, ln = lane & 15;
    const int xh = blockIdx.x, h = blockIdx.y, b = blockIdx.z;
    const int x0 = xh * 64;
    __shared__ __align__(16) ushortT sbuf[8 * 3 * 66 * 8];

    floatx4 acc[3][4];
    #pragma unroll
    for (int mt = 0; mt < 3; ++mt)
        #pragma unroll
        for (int nt = 0; nt < 4; ++nt)
            #pragma unroll
            for (int r = 0; r < 4; ++r) acc[mt][nt][r] = 0.f;

    for (int s = 0; s < 4; ++s) {
        __syncthreads();
        for (int it = 0; it < 7; ++it) {
            int idx = threadIdx.x + it * 256;
            if (idx < 1584) {
                int col = idx % 66, t2 = idx / 66;
                int r = t2 % 3, icg = t2 / 3;
                const ushortT* g = a16 +
                    (((size_t)(b * 32 + s * 8 + icg) * 130 + (h + r)) * 130 + (x0 + col)) * 8;
                *(short8*)(sbuf + (size_t)idx * 8) = *(const short8*)g;
            }
        }
        __syncthreads();
        #pragma unroll
        for (int tap = 0; tap < 9; ++tap) {
            const int ky = tap / 3, kx = tap % 3;
            #pragma unroll
            for (int icc = 0; icc < 2; ++icc) {
                const int icgl = icc * 4 + sub;
                short8 Bf[4];
                #pragma unroll
                for (int nt = 0; nt < 4; ++nt) {
                    int c = nt * 16 + ln + kx;
                    Bf[nt] = *(const short8*)(sbuf + ((icgl * 3 + ky) * 66 + c) * 8);
                }
                const int g = s * 8 + icc * 4 + sub;
                short8 Af[3];
                #pragma unroll
                for (int mt = 0; mt < 3; ++mt) {
                    int m = wv * 48 + mt * 16 + ln;
                    Af[mt] = *(const short8*)(wA + (((size_t)tap * 32 + g) * 192 + m) * 8);
                }
                #pragma unroll
                for (int mt = 0; mt < 3; ++mt)
                    #pragma unroll
                    for (int nt = 0; nt < 4; ++nt)
                        acc[mt][nt] = __builtin_amdgcn_mfma_f32_16x16x32_bf16(
                            Af[mt], Bf[nt], acc[mt][nt], 0, 0, 0);
            }
        }
    }
    #pragma unroll
    for (int mt = 0; mt < 3; ++mt)
        #pragma unroll
        for (int nt = 0; nt < 4; ++nt)
            #pragma unroll
            for (int r = 0; r < 4; ++r) {
                int Mi = wv * 48 + mt * 16 + sub * 4 + r;
                int px = x0 + nt * 16 + ln;
                float v = acc[mt][nt][r] + cb[Mi];
                feats[((size_t)b * 192 + Mi) * HW + h * WIMG + px] = fmaxf(v, 0.f);
            }
}

// ---------------- head 3x3 convs (64 -> 3/12/3) -> d_out ch 0..17 -----------
__global__ __launch_bounds__(256) void conv_head_kernel(
    const float* __restrict__ feats, const float* __restrict__ hwt_all,
    const float* __restrict__ chb, const float* __restrict__ ohb,
    const float* __restrict__ fhb, float* __restrict__ out)
{
    const int tx = threadIdx.x & 15, ty = threadIdx.x >> 4;
    const int w0 = blockIdx.x << 4, h0 = blockIdx.y << 4;
    const int br = blockIdx.z % 3, b = blockIdx.z / 3;
    const int cnt = (br == 1) ? 12 : 3;
    const int mapb = (br == 0) ? 0 : (br == 1) ? 3 : 15;
    const float* bias = (br == 0) ? chb : (br == 1) ? ohb : fhb;
    const float* hwt = hwt_all + br * 6912;
    __shared__ float tile[4][18][18];
    float acc[12];
    #pragma unroll
    for (int j = 0; j < 12; ++j) acc[j] = (j < cnt) ? bias[j] : 0.f;
    const float* fb = feats + ((size_t)b * 192 + br * 64) * HW;
    for (int c0 = 0; c0 < 64; c0 += 4) {
        __syncthreads();
        for (int i = threadIdx.x; i < 1296; i += 256) {
            int cc = i / 324, r = (i % 324) / 18, col = i % 18;
            int gh = h0 + r - 1, gw = w0 + col - 1;
            float v = 0.f;
            if ((unsigned)gh < 128u && (unsigned)gw < 128u)
                v = fb[(c0 + cc) * HW + gh * WIMG + gw];
            tile[cc][r][col] = v;
        }
        __syncthreads();
        #pragma unroll
        for (int cc = 0; cc < 4; ++cc) {
            float in[9];
            #pragma unroll
            for (int ky = 0; ky < 3; ++ky)
                #pragma unroll
                for (int kx = 0; kx < 3; ++kx)
                    in[ky * 3 + kx] = tile[cc][ty + ky][tx + kx];
            const float* wr = hwt + (c0 + cc) * 108;
            #pragma unroll
            for (int k = 0; k < 9; ++k)
                #pragma unroll
                for (int j = 0; j < 12; ++j)
                    acc[j] = fmaf(wr[k * 12 + j], in[k], acc[j]);
        }
    }
    float* ob = out + ((size_t)b * 26 + mapb) * HW + (h0 + ty) * WIMG + (w0 + tx);
    #pragma unroll
    for (int j = 0; j < 12; ++j)
        if (j < cnt) ob[j * HW] = acc[j];
}

// ----------------------------- q via bf16 MFMA ------------------------------
__global__ __launch_bounds__(256) void q_mfma(float* __restrict__ ws)
{
    const int wv = threadIdx.x >> 6, lane = threadIdx.x & 63;
    const int sub = lane >> 4, ln = lane & 15;
    const int px0 = blockIdx.x * 64, b = blockIdx.y;
    const ushortT* wQ = (const ushortT*)(ws + OFF_QWT);
    const ushortT* a16 = (const ushortT*)(ws + OFF_A16);
    const float* qb = ws + OFF_QB;
    __shared__ __align__(16) ushortT xb[32 * 64 * 8];

    const int mypx = threadIdx.x & 63, q4 = threadIdx.x >> 6;
    const int gpx = px0 + mypx, hh = gpx >> 7, ww = gpx & 127;
    #pragma unroll
    for (int g2 = 0; g2 < 8; ++g2) {
        int g = q4 * 8 + g2;
        short8 v = *(const short8*)(a16 +
            (((size_t)(b * 32 + g) * 130 + (hh + 1)) * 130 + (ww + 1)) * 8);
        *(short8*)(xb + ((size_t)g * 64 + mypx) * 8) = v;
    }
    __syncthreads();

    floatx4 acc[4];
    #pragma unroll
    for (int mt = 0; mt < 4; ++mt)
        #pragma unroll
        for (int r = 0; r < 4; ++r) acc[mt][r] = 0.f;
    #pragma unroll
    for (int kk = 0; kk < 8; ++kk) {
        short8 Bf = *(const short8*)(xb + (((kk * 4 + sub) * 64) + wv * 16 + ln) * 8);
        #pragma unroll
        for (int mt = 0; mt < 4; ++mt) {
            short8 Af = *(const short8*)(wQ + (((kk * 4 + sub) * 64) + mt * 16 + ln) * 8);
            acc[mt] = __builtin_amdgcn_mfma_f32_16x16x32_bf16(Af, Bf, acc[mt], 0, 0, 0);
        }
    }
    float* q = ws + OFF_Q + (size_t)b * 64 * HW;
    #pragma unroll
    for (int mt = 0; mt < 4; ++mt)
        #pragma unroll
        for (int r = 0; r < 4; ++r) {
            int Mi = mt * 16 + sub * 4 + r;
            q[(size_t)Mi * HW + px0 + wv * 16 + ln] = fmaxf(acc[mt][r] + qb[Mi], 0.f);
        }
}

// ------------- kv as sparse-tap conv via bf16 MFMA --------------------------
template<int BR, int NGRP, int NTAP, int ROWS, int COLS, int XMIN, int NCHUNK,
         int NPH, int UBASE>
__global__ __launch_bounds__(256) void kv_conv(
    const ushortT* __restrict__ b16, const ushortT* __restrict__ wU0,
    const float* __restrict__ geo, ushortT* __restrict__ kvout)
{
    const int wv = threadIdx.x >> 6, lane = threadIdx.x & 63;
    const int sub = lane >> 4, ln = lane & 15;
    const int x0 = blockIdx.x * 64, h = blockIdx.y, b = blockIdx.z;
    __shared__ __align__(16) ushortT sbuf[NGRP * ROWS * COLS * 8];

    floatx4 acc[2][4];
    #pragma unroll
    for (int mt = 0; mt < 2; ++mt)
        #pragma unroll
        for (int nt = 0; nt < 4; ++nt)
            #pragma unroll
            for (int r = 0; r < 4; ++r) acc[mt][nt][r] = 0.f;

    #pragma unroll
    for (int ph = 0; ph < NPH; ++ph) {
        const ushortT* wU = wU0 + (size_t)ph * (NCHUNK * 4 * 1024);
        __syncthreads();
        constexpr int NELEM = NGRP * ROWS * COLS;
        for (int it = 0; it < (NELEM + 255) / 256; ++it) {
            int idx = threadIdx.x + it * 256;
            if (idx < NELEM) {
                int col = idx % COLS, t2 = idx / COLS;
                int r = t2 % ROWS, grp = t2 / ROWS;
                int dy = (ROWS == 6) ? ((r < 3) ? r - 3 : r - 2) : (r - ROWS / 2);
                const ushortT* g = b16 +
                    (((size_t)(b * 28 + UBASE + ph * NGRP + grp) * 134 + (h + dy + 3)) * 134
                     + (x0 + col + XMIN + 3)) * 8;
                *(short8*)(sbuf + (size_t)idx * 8) = *(const short8*)g;
            }
        }
        __syncthreads();
        #pragma unroll
        for (int k = 0; k < NCHUNK; ++k) {
            int u = k * 4 + sub;
            int t = u / NGRP, g = u - t * NGRP;
            if (t >= NTAP) t = 0;  // padded units: A weights are zero
            int dxv, ry;
            if (BR == 0)      { dxv = t % 3 - 1; ry = t / 3; }
            else if (BR == 1) { dxv = tapX_cor[t]; ry = tapR_cor[t]; }
            else              { dxv = t % 5 - 2; ry = t / 5; }
            int bbase = (g * ROWS + ry) * COLS + (dxv - XMIN);
            short8 Bf[4];
            #pragma unroll
            for (int nt = 0; nt < 4; ++nt)
                Bf[nt] = *(const short8*)(sbuf + (bbase + nt * 16 + ln) * 8);
            short8 Af[2];
            #pragma unroll
            for (int mt = 0; mt < 2; ++mt)
                Af[mt] = *(const short8*)(wU + ((size_t)u * 128 + wv * 32 + mt * 16 + ln) * 8);
            #pragma unroll
            for (int mt = 0; mt < 2; ++mt)
                #pragma unroll
                for (int nt = 0; nt < 4; ++nt)
                    acc[mt][nt] = __builtin_amdgcn_mfma_f32_16x16x32_bf16(
                        Af[mt], Bf[nt], acc[mt][nt], 0, 0, 0);
        }
    }
    // epilogue: + GA*fx + GB*fy + GC (bias folded), relu, bf16 store
    const float fy = (h + 0.5f) * 0.0078125f;
    #pragma unroll
    for (int mt = 0; mt < 2; ++mt)
        #pragma unroll
        for (int nt = 0; nt < 4; ++nt) {
            int px = x0 + nt * 16 + ln;
            float fx = (px + 0.5f) * 0.0078125f;
            #pragma unroll
            for (int r = 0; r < 4; ++r) {
                int Mi = wv * 32 + mt * 16 + sub * 4 + r;
                float v = acc[mt][nt][r] + geo[Mi] * fx + geo[128 + Mi] * fy + geo[256 + Mi];
                kvout[((size_t)(BR * 4 + b) * 128 + Mi) * HW + h * WIMG + px] =
                    f2bf(fmaxf(v, 0.f));
            }
        }
}

// ---------- attention softmax + p1(MFMA, K=320) + relu + p2 -> out ----------
__global__ __launch_bounds__(256) void attn_pred_mfma(
    float* __restrict__ ws, const float* __restrict__ p2w,
    const float* __restrict__ p2b, float* __restrict__ out)
{
    const int wv = threadIdx.x >> 6, lane = threadIdx.x & 63;
    const int sub = lane >> 4, ln = lane & 15;
    const int px0 = blockIdx.x * 64, b = blockIdx.y;
    const ushortT* wP1 = (const ushortT*)(ws + OFF_P1WT);
    const ushortT* a16 = (const ushortT*)(ws + OFF_A16);
    const ushortT* kv = (const ushortT*)(ws + OFF_KV);
    const float* p1b = ws + OFF_P1B;
    __shared__ __align__(16) ushortT xbuf[40 * 64 * 8];

    const int mypx = threadIdx.x & 63, nh = threadIdx.x >> 6;
    const int gpx = px0 + mypx, hh = gpx >> 7, ww = gpx & 127;
    #pragma unroll
    for (int g2 = 0; g2 < 8; ++g2) {
        int g = nh * 8 + g2;
        short8 v = *(const short8*)(a16 +
            (((size_t)(b * 32 + g) * 130 + (hh + 1)) * 130 + (ww + 1)) * 8);
        *(short8*)(xbuf + ((size_t)g * 64 + mypx) * 8) = v;
    }
    {
        const float* q = ws + OFF_Q + ((size_t)b * 64 + nh * 16) * HW + gpx;
        float l[3];
        #pragma unroll
        for (int br = 0; br < 3; ++br) {
            float s = 0.f;
            #pragma unroll
            for (int ko = 0; ko < 16; ++ko)
                s = fmaf(q[(size_t)ko * HW],
                         bf2f(kv[(size_t)((br * 4 + b) * 128 + nh * 16 + ko) * HW + gpx]), s);
            l[br] = s;
        }
        float m = fmaxf(l[0], fmaxf(l[1], l[2]));
        float e0 = __expf(l[0] - m), e1 = __expf(l[1] - m), e2 = __expf(l[2] - m);
        float inv = 1.f / (e0 + e1 + e2);
        float aw0 = e0 * inv, aw1 = e1 * inv, aw2 = e2 * inv;
        #pragma unroll
        for (int vap = 0; vap < 8; ++vap) {
            int va0 = vap * 2, va1 = vap * 2 + 1;
            float a0 =
                aw0 * bf2f(kv[(size_t)((0 * 4 + b) * 128 + 64 + nh * 16 + va0) * HW + gpx]) +
                aw1 * bf2f(kv[(size_t)((1 * 4 + b) * 128 + 64 + nh * 16 + va0) * HW + gpx]) +
                aw2 * bf2f(kv[(size_t)((2 * 4 + b) * 128 + 64 + nh * 16 + va0) * HW + gpx]);
            float a1 =
                aw0 * bf2f(kv[(size_t)((0 * 4 + b) * 128 + 64 + nh * 16 + va1) * HW + gpx]) +
                aw1 * bf2f(kv[(size_t)((1 * 4 + b) * 128 + 64 + nh * 16 + va1) * HW + gpx]) +
                aw2 * bf2f(kv[(size_t)((2 * 4 + b) * 128 + 64 + nh * 16 + va1) * HW + gpx]);
            int g = 32 + nh * 2 + (vap >> 2), wo = vap & 3;
            ((unsigned*)xbuf)[(g * 64 + mypx) * 4 + wo] = packbf(a0, a1);
        }
    }
    __syncthreads();

    floatx4 acc[4][4];
    #pragma unroll
    for (int mt = 0; mt < 4; ++mt)
        #pragma unroll
        for (int nt = 0; nt < 4; ++nt)
            #pragma unroll
            for (int r = 0; r < 4; ++r) acc[mt][nt][r] = 0.f;
    #pragma unroll
    for (int kk = 0; kk < 10; ++kk) {
        short8 Bf[4];
        #pragma unroll
        for (int nt = 0; nt < 4; ++nt)
            Bf[nt] = *(const short8*)(xbuf + (((kk * 4 + sub) * 64) + nt * 16 + ln) * 8);
        #pragma unroll
        for (int mt = 0; mt < 4; ++mt) {
            short8 Af = *(const short8*)(wP1 +
                (((size_t)(kk * 4 + sub) * 256) + wv * 64 + mt * 16 + ln) * 8);
            #pragma unroll
            for (int nt = 0; nt < 4; ++nt)
                acc[mt][nt] = __builtin_amdgcn_mfma_f32_16x16x32_bf16(Af, Bf[nt], acc[mt][nt], 0, 0, 0);
        }
    }

    float po0[4] = {0.f, 0.f, 0.f, 0.f}, po1[4] = {0.f, 0.f, 0.f, 0.f};
    #pragma unroll
    for (int mt = 0; mt < 4; ++mt)
        #pragma unroll
        for (int r = 0; r < 4; ++r) {
            int oc = mt * 16 + sub * 4 + r;
            float bias = p1b[wv * 64 + oc];
            float w0 = p2w[(wv * 2 + 0) * 64 + oc];
            float w1 = p2w[(wv * 2 + 1) * 64 + oc];
            #pragma unroll
            for (int nt = 0; nt < 4; ++nt) {
                float hv = fmaxf(acc[mt][nt][r] + bias, 0.f);
                po0[nt] = fmaf(w0, hv, po0[nt]);
                po1[nt] = fmaf(w1, hv, po1[nt]);
            }
        }
    #pragma unroll
    for (int nt = 0; nt < 4; ++nt) {
        po0[nt] += __shfl_xor(po0[nt], 16);
        po0[nt] += __shfl_xor(po0[nt], 32);
        po1[nt] += __shfl_xor(po1[nt], 16);
        po1[nt] += __shfl_xor(po1[nt], 32);
    }
    if (sub == 0) {
        #pragma unroll
        for (int nt = 0; nt < 4; ++nt) {
            int px = px0 + nt * 16 + ln;
            out[((size_t)b * 26 + 18 + wv * 2 + 0) * HW + px] = po0[nt] + p2b[wv * 2 + 0];
            out[((size_t)b * 26 + 18 + wv * 2 + 1) * HW + px] = po1[nt] + p2b[wv * 2 + 1];
        }
    }
}

// ---------------------------------------------------------------------------
extern "C" void kernel_launch(void* const* d_in, const int* in_sizes, int n_in,
                              void* d_out, int out_size, void* d_ws, size_t ws_size,
                              hipStream_t stream) {
    (void)in_sizes; (void)n_in; (void)out_size; (void)ws_size;
    float* ws  = (float*)d_ws;
    float* out = (float*)d_out;
    const float* base = (const float*)d_in[0];
    P53 ptrs;
    for (int i = 0; i < 53; ++i) ptrs.p[i] = (const float*)d_in[i];

    ushortT* a16 = (ushortT*)(ws + OFF_A16);
    ushortT* b16 = (ushortT*)(ws + OFF_B16);
    ushortT* kvb = (ushortT*)(ws + OFF_KV);

    prep_kernel<<<4088, 256, 0, stream>>>(ptrs, ws);
    pass_a<<<8450, 256, 0, stream>>>(base, a16);
    conv_base_mfma<<<dim3(2, 128, 4), 256, 0, stream>>>(
        a16, (const ushortT*)(ws + OFF_CWT), ws + OFF_CB, ws + OFF_FEATS);
    conv_head_kernel<<<dim3(8, 8, 12), 256, 0, stream>>>(ws + OFF_FEATS, ws + OFF_HWT,
                                                         (const float*)d_in[6],
                                                         (const float*)d_in[12],
                                                         (const float*)d_in[18], out);
    q_mfma<<<dim3(256, 4), 256, 0, stream>>>(ws);
    pass_b<<<7856, 256, 0, stream>>>(ws + OFF_FEATS, out, b16);

    const ushortT* kvw = (const ushortT*)(ws + OFF_KVW);
    kv_conv<0, 9, 9, 3, 66, -1, 21, 1, 0><<<dim3(2, 128, 4), 256, 0, stream>>>(
        b16, kvw, ws + OFF_GEO, kvb);
    kv_conv<1, 5, 16, 6, 70, -3, 20, 2, 9><<<dim3(2, 128, 4), 256, 0, stream>>>(
        b16, kvw + 86016, ws + OFF_GEO + 384, kvb);
    kv_conv<2, 9, 25, 5, 68, -2, 57, 1, 19><<<dim3(2, 128, 4), 256, 0, stream>>>(
        b16, kvw + 249856, ws + OFF_GEO + 768, kvb);

    attn_pred_mfma<<<dim3(256, 4), 256, 0, stream>>>(ws, (const float*)d_in[51],
                                                     (const float*)d_in[52], out);
}